// Round 2
// baseline (335.948 us; speedup 1.0000x reference)
//
#include <hip/hip_runtime.h>
#include <float.h>

#define NQ    1024
#define JTOT  5120
#define MEML  4096
#define SCL2  0.18033688011112042f   /* 0.125 * log2(e) */

typedef __attribute__((ext_vector_type(8))) short bf16x8;
typedef __attribute__((ext_vector_type(8))) unsigned short ush8;
typedef __attribute__((ext_vector_type(4))) unsigned short ush4;
typedef __attribute__((ext_vector_type(4))) float f32x4;

static __device__ __forceinline__ unsigned short f2bf(float x) {
    union { float f; unsigned u; } v; v.f = x;
    unsigned r = (v.u + 0x7fffu + ((v.u >> 16) & 1u)) >> 16;   // RNE
    return (unsigned short)r;
}
// pack trunc-bf16(f0) (low) | trunc-bf16(f1) (high)
static __device__ __forceinline__ unsigned pack2(float f0, float f1) {
    union { float f; unsigned u; } a, b; a.f = f1; b.f = f0;
    return __builtin_amdgcn_perm(a.u, b.u, 0x07060302u);
}

static __device__ __forceinline__ void gld16(const void* g, void* l) {
    __builtin_amdgcn_global_load_lds(
        (const __attribute__((address_space(1))) unsigned int*)g,
        (__attribute__((address_space(3))) unsigned int*)l, 16, 0, 0);
}

// ---------------------------------------------------------------------------
// prep: one launch. blocks [0,1024): x->bf16; [1024,5120): mem->bf16;
// [5120,5160): mask->bias; [5160,9256): W transpose.
// (Writes NO final outputs — early-graph output writes get clobbered by the
// harness re-poison; new_mem is written by the LAST dispatch. R6 post-mortem.)
// ---------------------------------------------------------------------------
__global__ __launch_bounds__(256)
void prep_kernel(const float* __restrict__ x, const float* __restrict__ mem,
                 const unsigned char* __restrict__ mask,
                 const float* __restrict__ W0, const float* __restrict__ W1,
                 const float* __restrict__ W2, const float* __restrict__ W3,
                 unsigned short* __restrict__ xb, unsigned short* __restrict__ memb,
                 unsigned short* __restrict__ wt, float* __restrict__ mbp)
{
    __shared__ float Ts[32][33];
    const int bid = blockIdx.x;
    const int t   = threadIdx.x;
    if (bid < 5120) {
        const float* src = (bid < 1024) ? x : mem;
        unsigned short* dst = (bid < 1024) ? xb : memb;
        const size_t i = (size_t)((bid < 1024) ? bid : bid - 1024) * 2048 + t * 8;
        float4 a = *(const float4*)(src + i);
        float4 b = *(const float4*)(src + i + 4);
        ush8 o;
        o[0] = f2bf(a.x); o[1] = f2bf(a.y); o[2] = f2bf(a.z); o[3] = f2bf(a.w);
        o[4] = f2bf(b.x); o[5] = f2bf(b.y); o[6] = f2bf(b.z); o[7] = f2bf(b.w);
        *(ush8*)(dst + i) = o;
    } else if (bid < 5160) {
        const int i = (bid - 5120) * 256 + t;
        mbp[i] = mask[i] ? -1.0e30f : 0.0f;
    } else {
        const int idx = bid - 5160;
        const int z   = idx >> 10;
        const int rem = idx & 1023;
        const float* W = (z == 0) ? W0 : (z == 1) ? W1 : (z == 2) ? W2 : W3;
        unsigned short* D = wt + (size_t)z * 1024 * 1024;
        const int n0 = (rem & 31) * 32, k0 = (rem >> 5) * 32;
        const int tr = t >> 3, tc = (t & 7) * 4;
        float4 v = *(const float4*)(W + (size_t)(k0 + tr) * 1024 + n0 + tc);
        Ts[tr][tc + 0] = v.x; Ts[tr][tc + 1] = v.y;
        Ts[tr][tc + 2] = v.z; Ts[tr][tc + 3] = v.w;
        __syncthreads();
        ush4 o;
        o[0] = f2bf(Ts[tc + 0][tr]); o[1] = f2bf(Ts[tc + 1][tr]);
        o[2] = f2bf(Ts[tc + 2][tr]); o[3] = f2bf(Ts[tc + 3][tr]);
        *(ush4*)(D + (size_t)(n0 + tr) * 1024 + k0 + tc) = o;
    }
}

// ---------------------------------------------------------------------------
// Merged q/k/v GEMM — 256x256 tile, BK=64, 8-wave (2Mx4N), phased schedule
// (T2 swizzle + T3/T4 counted-vmcnt + T5 setprio).
// blocks [0,96) = x @ {Wq,Wk,Wv}; [96,352) = mem @ {Wk,Wv}.
// R2 fix: barriers are __builtin_amdgcn_s_barrier() (raw builtin — NO
// compiler-inserted vmcnt(0) drain), waitcnts are clobber-free inline asm.
// R1's asm("s_barrier":::"memory") made SIInsertWaitcnts drain ALL vmem
// before every barrier (8x/K-step) -> per-phase full-latency stall.
// Stage regions ordered to match per-phase consumption:
//   ph0: reads B(all)+A[m0..1] | stages A2(t+1 -> other buf)
//   ph1: reads A[m2..3]        | stages B0(t+2 -> this buf)   (B freed @ph0)
//   ph2: reads A[m4..5]        | stages A1(t+2)               (A[0,64) freed @ph1)
//   ph3: reads A[m6..7]        | stages B1(t+2); vmcnt(6) after MFMA
// Each phase: reads+stage -> barrier -> lgkmcnt(0)+sched_barrier -> 16 MFMA
// -> [vmcnt(6) @ph3] -> barrier. Reads of any region drain (lgkmcnt(0)) one
// full barrier before the stage that overwrites that region issues.
// ---------------------------------------------------------------------------
__global__ __launch_bounds__(512, 2)
void mgemm01_kernel(const unsigned short* __restrict__ xb,
                    const unsigned short* __restrict__ memb,
                    const unsigned short* __restrict__ wt,
                    unsigned short* __restrict__ Qb, unsigned short* __restrict__ Kb,
                    unsigned short* __restrict__ Vb,
                    const float* __restrict__ rel_table, const int* __restrict__ rel_idxs)
{
    __shared__ unsigned short Al[2][256 * 64];
    __shared__ unsigned short Bl[2][256 * 64];

    const int t    = threadIdx.x;
    const int lane = t & 63;
    const int w    = t >> 6;          // 0..7
    const int wr   = w >> 2;          // 0..1  (M half)
    const int wc   = w & 3;           // 0..3  (N quarter)
    const int l15  = lane & 15;
    const int quad = lane >> 4;
    const int l7   = l15 & 7;
    const int srow = lane >> 3;                 // staging row within 8-row group
    const int scol = ((lane & 7) ^ srow) << 3;  // pre-swizzled source chunk

    int bid = blockIdx.x;
    int mode, bx, by;
    if (bid < 96) { mode = 0; bx = bid % 12; by = bid / 12; }
    else          { bid -= 96; mode = 1; bx = bid & 7; by = bid >> 3; }
    const int mat = bx >> 2;
    const int n0  = (bx & 3) << 8;
    const int m0  = by << 8;
    const unsigned short* Ag = (mode == 0) ? xb : memb;
    const unsigned short* Bg = wt + (size_t)((mode == 0) ? mat : mat + 1) * 1024 * 1024;

    const size_t abase = (size_t)(m0 + srow) * 1024 + scol;
    const size_t bbase = (size_t)(n0 + srow) * 1024 + scol;

    // stage units: 2 gld16/wave each (vmcnt counts instructions: 1 unit = 2)
    auto stageB0 = [&](int b, int kt) {               // B rows [0,128)
        const int kb = kt << 6, r0 = w * 16;
        gld16(Bg + bbase + (size_t)r0 * 1024 + kb,       &Bl[b][r0 * 64]);
        gld16(Bg + bbase + (size_t)(r0 + 8) * 1024 + kb, &Bl[b][(r0 + 8) * 64]);
    };
    auto stageB1 = [&](int b, int kt) {               // B rows [128,256)
        const int kb = kt << 6, r0 = 128 + w * 16;
        gld16(Bg + bbase + (size_t)r0 * 1024 + kb,       &Bl[b][r0 * 64]);
        gld16(Bg + bbase + (size_t)(r0 + 8) * 1024 + kb, &Bl[b][(r0 + 8) * 64]);
    };
    auto stageA1 = [&](int b, int kt) {               // A rows [0,64) u [128,192)
        const int kb = kt << 6, r0 = w * 8, r1 = 128 + w * 8;
        gld16(Ag + abase + (size_t)r0 * 1024 + kb, &Al[b][r0 * 64]);
        gld16(Ag + abase + (size_t)r1 * 1024 + kb, &Al[b][r1 * 64]);
    };
    auto stageA2 = [&](int b, int kt) {               // A rows [64,128) u [192,256)
        const int kb = kt << 6, r0 = 64 + w * 8, r1 = 192 + w * 8;
        gld16(Ag + abase + (size_t)r0 * 1024 + kb, &Al[b][r0 * 64]);
        gld16(Ag + abase + (size_t)r1 * 1024 + kb, &Al[b][r1 * 64]);
    };

    f32x4 acc[8][4];
    #pragma unroll
    for (int i = 0; i < 8; i++)
        #pragma unroll
        for (int j = 0; j < 4; j++) acc[i][j] = (f32x4){0.f, 0.f, 0.f, 0.f};

    // prologue: tile0 complete (4 units) + tile1 {B0,A1,B1} = 14 loads;
    // vmcnt(6) retires the oldest 8 = all of tile0.
    stageB0(0, 0); stageB1(0, 0); stageA1(0, 0); stageA2(0, 0);
    stageB0(1, 1); stageA1(1, 1); stageB1(1, 1);
    asm volatile("s_waitcnt vmcnt(6)");
    __builtin_amdgcn_s_barrier();

    bf16x8 bfr[4][2];

#define PHASE(P, MB, STAGE, VMW)                                                   \
    {                                                                              \
        const int Ra0 = (wr * 128 + (MB) * 16 + l15) * 64;                         \
        const int Ra1 = Ra0 + 16 * 64;                                             \
        const bf16x8 a0 = *(const bf16x8*)&Al[P][Ra0 + ((quad ^ l7) << 3)];        \
        const bf16x8 a1 = *(const bf16x8*)&Al[P][Ra0 + (((4 | quad) ^ l7) << 3)];  \
        const bf16x8 a2 = *(const bf16x8*)&Al[P][Ra1 + ((quad ^ l7) << 3)];        \
        const bf16x8 a3 = *(const bf16x8*)&Al[P][Ra1 + (((4 | quad) ^ l7) << 3)];  \
        STAGE;                                                                     \
        __builtin_amdgcn_s_barrier();                                              \
        asm volatile("s_waitcnt lgkmcnt(0)");                                      \
        __builtin_amdgcn_sched_barrier(0);                                         \
        __builtin_amdgcn_s_setprio(1);                                             \
        _Pragma("unroll")                                                          \
        for (int n = 0; n < 4; n++) {                                              \
            acc[(MB)][n]     = __builtin_amdgcn_mfma_f32_16x16x32_bf16(a0, bfr[n][0], acc[(MB)][n], 0, 0, 0);     \
            acc[(MB)][n]     = __builtin_amdgcn_mfma_f32_16x16x32_bf16(a1, bfr[n][1], acc[(MB)][n], 0, 0, 0);     \
            acc[(MB) + 1][n] = __builtin_amdgcn_mfma_f32_16x16x32_bf16(a2, bfr[n][0], acc[(MB) + 1][n], 0, 0, 0); \
            acc[(MB) + 1][n] = __builtin_amdgcn_mfma_f32_16x16x32_bf16(a3, bfr[n][1], acc[(MB) + 1][n], 0, 0, 0); \
        }                                                                          \
        __builtin_amdgcn_s_setprio(0);                                             \
        VMW;                                                                       \
        __builtin_amdgcn_s_barrier();                                              \
    }

#define KSTEP(P, S0, S1, S2, S3, VMW)                                              \
    {                                                                              \
        _Pragma("unroll")                                                          \
        for (int n = 0; n < 4; n++) {                                              \
            const int Rb = (wc * 64 + n * 16 + l15) * 64;                          \
            bfr[n][0] = *(const bf16x8*)&Bl[P][Rb + ((quad ^ l7) << 3)];           \
            bfr[n][1] = *(const bf16x8*)&Bl[P][Rb + (((4 | quad) ^ l7) << 3)];     \
        }                                                                          \
        PHASE(P, 0, S0, {})                                                        \
        PHASE(P, 2, S1, {})                                                        \
        PHASE(P, 4, S2, {})                                                        \
        PHASE(P, 6, S3, VMW)                                                       \
    }

    // main loop: K = 1024 -> 16 K-tiles; steady state has no branches.
    #pragma unroll 2
    for (int tk = 0; tk < 14; ++tk) {
        const int p = tk & 1;
        KSTEP(p,
              stageA2(p ^ 1, tk + 1),
              stageB0(p, tk + 2),
              stageA1(p, tk + 2),
              stageB1(p, tk + 2),
              asm volatile("s_waitcnt vmcnt(6)"));
    }
    // tk = 14: finish tile15's staging (A2 only), then drain.
    KSTEP(0, stageA2(1, 15), (void)0, (void)0, (void)0,
          asm volatile("s_waitcnt vmcnt(0)"));
    // tk = 15: pure compute.
    KSTEP(1, (void)0, (void)0, (void)0, (void)0, (void)0);

#undef KSTEP
#undef PHASE

    // epilogue — identical routing to the verified 128² version, 8x4 fragments.
    const bool isQ = (mode == 0) && (mat == 0);
    const bool isK = (mode == 0) ? (mat == 1) : (mat == 0);
    if (!isQ && !isK) {                              // V path
        #pragma unroll
        for (int m = 0; m < 8; m++) {
            const int r0 = m0 + wr * 128 + m * 16 + quad * 4;
            const int bb = (mode == 0) ? (r0 >> 10) : (r0 >> 12);
            const int j0 = (mode == 0) ? 4096 + (r0 & 1023) : (r0 & 4095);
            #pragma unroll
            for (int n = 0; n < 4; n++) {
                const int col = n0 + wc * 64 + n * 16 + l15;
                ush4 o;
                o[0] = f2bf(acc[m][n][0]); o[1] = f2bf(acc[m][n][1]);
                o[2] = f2bf(acc[m][n][2]); o[3] = f2bf(acc[m][n][3]);
                *(ush4*)(Vb + ((size_t)((bb * 16 + (col >> 6)) * 64 + (col & 63))) * JTOT + j0) = o;
            }
        }
    } else {
        #pragma unroll
        for (int m = 0; m < 8; m++)
            #pragma unroll
            for (int reg = 0; reg < 4; reg++) {
                const int r = m0 + wr * 128 + m * 16 + quad * 4 + reg;
                int bb, idx, chunk;
                if (mode == 0) { bb = r >> 10; idx = isK ? 4096 + (r & 1023) : (r & 1023); chunk = 4; }
                else           { bb = r >> 12; idx = r & 4095; chunk = idx >> 10; }
                #pragma unroll
                for (int n = 0; n < 4; n++) {
                    const int col = n0 + wc * 64 + n * 16 + l15;
                    const int hh = col >> 6, dh = col & 63;
                    float v = acc[m][n][reg];
                    if (isK) {
                        v += rel_table[rel_idxs[chunk] * 16 + hh];
                        Kb[((size_t)(bb * 16 + hh) * JTOT + idx) * 64 + dh] = f2bf(v);
                    } else {
                        Qb[((size_t)(bb * 16 + hh) * NQ + idx) * 64 + dh] = f2bf(v);
                    }
                }
            }
    }
}

// ---------------------------------------------------------------------------
// out = ao @ WoT + bo. 64x128 tile, BK=64, swizzled.
// z=1 blocks: copy x -> new_mem (LAST dispatch in graph — survives re-poison).
// ---------------------------------------------------------------------------
__global__ __launch_bounds__(256)
void mgemm2_kernel(const unsigned short* __restrict__ A,
                   const unsigned short* __restrict__ WT,
                   float* __restrict__ outF, const float* __restrict__ bo,
                   const float* __restrict__ x, float* __restrict__ newmem)
{
    __shared__ unsigned short Al[64 * 64];
    __shared__ unsigned short Bl[128 * 64];

    const int t = threadIdx.x;
    if (blockIdx.z == 1) {
        const int blk = blockIdx.y * 8 + blockIdx.x;      // 0..255
        const size_t base = (size_t)blk * 8192 + t * 4;
        #pragma unroll
        for (int i = 0; i < 8; i++)
            *(float4*)(newmem + base + (size_t)i * 1024) =
                *(const float4*)(x + base + (size_t)i * 1024);
        return;
    }

    const int lane = t & 63;
    const int w    = t >> 6;
    const int l15  = lane & 15;
    const int quad = lane >> 4;
    const int l7   = l15 & 7;
    const int n0   = blockIdx.x * 128;
    const int m0   = blockIdx.y * 64;

    f32x4 acc[4][2];
    #pragma unroll
    for (int i = 0; i < 4; i++)
        #pragma unroll
        for (int j = 0; j < 2; j++) acc[i][j] = (f32x4){0.f, 0.f, 0.f, 0.f};

    for (int k0 = 0; k0 < 1024; k0 += 64) {
        __syncthreads();
        #pragma unroll
        for (int it = 0; it < 2; it++) {
            const int lin  = it * 256 + t;
            const int row  = lin >> 3;
            const int colb = ((lin & 7) ^ (row & 7)) * 8;
            gld16(A + (size_t)(m0 + row) * 1024 + k0 + colb,
                  &Al[(size_t)(it * 256 + w * 64) * 8]);
        }
        #pragma unroll
        for (int it = 0; it < 4; it++) {
            const int lin  = it * 256 + t;
            const int row  = lin >> 3;
            const int colb = ((lin & 7) ^ (row & 7)) * 8;
            gld16(WT + (size_t)(n0 + row) * 1024 + k0 + colb,
                  &Bl[(size_t)(it * 256 + w * 64) * 8]);
        }
        __syncthreads();
        bf16x8 af[4][2], bfr[2][2];
        #pragma unroll
        for (int i = 0; i < 4; i++) {
            const int R = i * 16 + l15;
            af[i][0] = *(const bf16x8*)&Al[R * 64 + ((quad ^ l7) << 3)];
            af[i][1] = *(const bf16x8*)&Al[R * 64 + (((4 | quad) ^ l7) << 3)];
        }
        #pragma unroll
        for (int j = 0; j < 2; j++) {
            const int R = w * 32 + j * 16 + l15;
            bfr[j][0] = *(const bf16x8*)&Bl[R * 64 + ((quad ^ l7) << 3)];
            bfr[j][1] = *(const bf16x8*)&Bl[R * 64 + (((4 | quad) ^ l7) << 3)];
        }
        #pragma unroll
        for (int i = 0; i < 4; i++)
            #pragma unroll
            for (int j = 0; j < 2; j++) {
                acc[i][j] = __builtin_amdgcn_mfma_f32_16x16x32_bf16(af[i][0], bfr[j][0], acc[i][j], 0, 0, 0);
                acc[i][j] = __builtin_amdgcn_mfma_f32_16x16x32_bf16(af[i][1], bfr[j][1], acc[i][j], 0, 0, 0);
            }
    }

    #pragma unroll
    for (int i = 0; i < 4; i++)
        #pragma unroll
        for (int reg = 0; reg < 4; reg++) {
            const int r = m0 + i * 16 + quad * 4 + reg;
            #pragma unroll
            for (int j = 0; j < 2; j++) {
                const int col = n0 + w * 32 + j * 16 + l15;
                outF[(size_t)r * 1024 + col] = acc[i][j][reg] + bo[col];
            }
        }
}

// ---------------------------------------------------------------------------
// Flash attention, S^T formulation, 128-key tiles, swizzled 48 KB LDS.
// R9: NO online max — scores are bounded (|s*log2e| << 127, bf16 inputs), so
// softmax = exp2(s)/sum(exp2(s)) directly: per-lane-only loop (fma/exp/add/
// pack), l_i partial per lane, cross-quad reduce ONCE in epilogue.
// exp2 via __builtin_amdgcn_exp2f (bare v_exp_f32, not the ocml precise path).
// ---------------------------------------------------------------------------
__global__ __launch_bounds__(256)
void attn5_kernel(const unsigned short* __restrict__ qh,
                  const unsigned short* __restrict__ kh,
                  const unsigned short* __restrict__ vt,
                  const float* __restrict__ mb,
                  unsigned short* __restrict__ ao)
{
    __shared__ unsigned short Ks[128 * 64];   // [key][dh] swizzled (8-unit rows)
    __shared__ unsigned short Vs[64 * 128];   // [dh][key] swizzled (16-unit rows)
    __shared__ unsigned short Ps[64 * 128];   // [q][key]  swizzled (16-unit rows)

    const int t    = threadIdx.x;
    const int lane = t & 63;
    const int w    = t >> 6;
    const int l15  = lane & 15;
    const int quad = lane >> 4;
    const int l7   = l15 & 7;
    const int qt   = blockIdx.x;
    const int h    = blockIdx.y;
    const int b    = blockIdx.z;
    const int qbase = qt * 64;
    const int qg    = qbase + w * 16 + l15;

    const unsigned short* qrow = qh + (((size_t)(b * 16 + h) * NQ + qg) << 6);
    const bf16x8 bq0 = *(const bf16x8*)(qrow + quad * 8);
    const bf16x8 bq1 = *(const bf16x8*)(qrow + 32 + quad * 8);

    const int krow = t >> 3;
    const int kcol = (t & 7) * 8;
    const int ksw  = ((t & 7) ^ (krow & 7)) * 8;
    const int vrow = t >> 4;
    const int vu   = t & 15;
    const int vcol = vu * 8;
    const int vsw  = ((vu & 8) | ((vu ^ (vrow & 7)) & 7)) * 8;

    const unsigned short* kbase = kh + (((size_t)(b * 16 + h) * JTOT) << 6);
    const unsigned short* vbase = vt + (((size_t)(b * 16 + h)) << 6) * JTOT;
    const float* mbb = mb + b * JTOT;

    f32x4 oa[4];
    #pragma unroll
    for (int mt = 0; mt < 4; mt++) oa[mt] = (f32x4){0.f, 0.f, 0.f, 0.f};
    float l_i = 0.f;                           // per-lane partial (32 keys/tile)

    const int ntp = (qt + 66) >> 1;           // 128-key tiles (padded)

    ush8 kst[4], vst[4];
    #pragma unroll
    for (int p = 0; p < 4; p++)
        kst[p] = *(const ush8*)(kbase + ((size_t)(krow + 32 * p) << 6) + kcol);
    #pragma unroll
    for (int p = 0; p < 4; p++)
        vst[p] = *(const ush8*)(vbase + (size_t)(vrow + 16 * p) * JTOT + vcol);

    for (int jt = 0; jt < ntp; jt++) {
        const int jbase = jt * 128;
        __syncthreads();
        #pragma unroll
        for (int p = 0; p < 4; p++)
            *(ush8*)&Ks[(krow + 32 * p) * 64 + ksw] = kst[p];
        #pragma unroll
        for (int p = 0; p < 4; p++)
            *(ush8*)&Vs[(vrow + 16 * p) * 128 + vsw] = vst[p];
        __syncthreads();

        if (jt + 1 < ntp) {
            const int jb2 = jbase + 128;
            #pragma unroll
            for (int p = 0; p < 4; p++)
                kst[p] = *(const ush8*)(kbase + ((size_t)(jb2 + krow + 32 * p) << 6) + kcol);
            #pragma unroll
            for (int p = 0; p < 4; p++)
                vst[p] = *(const ush8*)(vbase + (size_t)(vrow + 16 * p) * JTOT + jb2 + vcol);
        }

        // St = K.Q^T : 128 keys x 16 q per wave
        f32x4 sa[8];
        #pragma unroll
        for (int mt2 = 0; mt2 < 8; mt2++) {
            const int ra = (mt2 * 16 + l15) * 64;
            const bf16x8 ak0 = *(const bf16x8*)&Ks[ra + ((quad ^ l7) << 3)];
            const bf16x8 ak1 = *(const bf16x8*)&Ks[ra + (((4 | quad) ^ l7) << 3)];
            f32x4 s = (f32x4){0.f, 0.f, 0.f, 0.f};
            s = __builtin_amdgcn_mfma_f32_16x16x32_bf16(ak0, bq0, s, 0, 0, 0);
            s = __builtin_amdgcn_mfma_f32_16x16x32_bf16(ak1, bq1, s, 0, 0, 0);
            sa[mt2] = s;
        }

        // scale (exp2 domain) + key-mask bias
        #pragma unroll
        for (int mt2 = 0; mt2 < 8; mt2++) {
            const float4 mv = *(const float4*)(mbb + jbase + mt2 * 16 + quad * 4);
            sa[mt2][0] = sa[mt2][0] * SCL2 + mv.x;
            sa[mt2][1] = sa[mt2][1] * SCL2 + mv.y;
            sa[mt2][2] = sa[mt2][2] * SCL2 + mv.z;
            sa[mt2][3] = sa[mt2][3] * SCL2 + mv.w;
        }
        // causal (+pad) mask: only the last tile contains the boundary
        if (jt == ntp - 1) {
            const int tl = qg + 4096 - jbase;
            #pragma unroll
            for (int mt2 = 0; mt2 < 8; mt2++)
                #pragma unroll
                for (int r = 0; r < 4; r++)
                    if (mt2 * 16 + quad * 4 + r > tl) sa[mt2][r] = -1.0e30f;
        }

        // softmax numerator: pure per-lane (no max, no cross-lane this tile)
        #pragma unroll
        for (int mt2 = 0; mt2 < 8; mt2++)
            #pragma unroll
            for (int r = 0; r < 4; r++) {
                const float pv = __builtin_amdgcn_exp2f(sa[mt2][r]);
                sa[mt2][r] = pv;
                l_i += pv;
            }

        // P -> Ps[q][key] (uint2 packed, truncation); same-wave rows, no barrier
        const int prow = (w * 16 + l15) * 128;
        #pragma unroll
        for (int mt2 = 0; mt2 < 8; mt2++) {
            const int u  = 2 * mt2 + (quad >> 1);
            const int up = (u & 8) | ((u ^ l7) & 7);
            uint2 pk;
            pk.x = pack2(sa[mt2][0], sa[mt2][1]);
            pk.y = pack2(sa[mt2][2], sa[mt2][3]);
            *(uint2*)&Ps[prow + up * 8 + (quad & 1) * 4] = pk;
        }

        // O^T += V^T.P^T
        #pragma unroll
        for (int s = 0; s < 4; s++) {
            const int u  = quad + 4 * s;
            const int up = (u & 8) | ((u ^ l7) & 7);
            const bf16x8 bp = *(const bf16x8*)&Ps[prow + up * 8];
            #pragma unroll
            for (int mt = 0; mt < 4; mt++) {
                const bf16x8 av = *(const bf16x8*)&Vs[(mt * 16 + l15) * 128 + up * 8];
                oa[mt] = __builtin_amdgcn_mfma_f32_16x16x32_bf16(av, bp, oa[mt], 0, 0, 0);
            }
        }
    }

    // epilogue: cross-quad l reduce (the 4 quads of the same l15 hold disjoint
    // key partials for q=qg), then normalize and store.
    float l = l_i;
    l += __shfl_xor(l, 16);
    l += __shfl_xor(l, 32);
    const float inv = 1.0f / l;
    unsigned short* arow = ao + ((size_t)(b * NQ + qg)) * 1024 + h * 64;
    #pragma unroll
    for (int mt = 0; mt < 4; mt++) {
        ush4 o;
        o[0] = f2bf(oa[mt][0] * inv); o[1] = f2bf(oa[mt][1] * inv);
        o[2] = f2bf(oa[mt][2] * inv); o[3] = f2bf(oa[mt][3] * inv);
        *(ush4*)(arow + mt * 16 + quad * 4) = o;
    }
}

// ---------------------------------------------------------------------------
extern "C" void kernel_launch(void* const* d_in, const int* in_sizes, int n_in,
                              void* d_out, int out_size, void* d_ws, size_t ws_size,
                              hipStream_t stream)
{
    const float* x        = (const float*)d_in[0];
    const float* mem      = (const float*)d_in[1];
    const unsigned char* mask = (const unsigned char*)d_in[2];
    const int*   rel_idxs = (const int*)d_in[3];
    const float* Wq       = (const float*)d_in[4];
    const float* Wk       = (const float*)d_in[5];
    const float* Wv       = (const float*)d_in[6];
    const float* Wo       = (const float*)d_in[7];
    const float* bo       = (const float*)d_in[8];
    const float* rel_table= (const float*)d_in[9];

    float* out = (float*)d_out;
    const size_t M1 = (size_t)1024 * 1024;
    unsigned short* xb   = (unsigned short*)d_ws;   //  2M
    unsigned short* memb = xb   + 2 * M1;           //  8M
    unsigned short* wt   = memb + 8 * M1;           //  4M
    unsigned short* qb   = wt   + 4 * M1;           //  2M  qh[b][h][q][dh]
    unsigned short* kb   = qb   + 2 * M1;           // 10M  kh[b][h][j][dh]
    unsigned short* vb   = kb   + 10 * M1;          // 10M  vt[b][h][dh][j]
    unsigned short* aob  = vb   + 10 * M1;          //  2M
    float* mbp = (float*)(aob + 2 * M1);            // 10240 floats

    prep_kernel<<<9256, 256, 0, stream>>>(
        x, mem, mask, Wq, Wk, Wv, Wo, xb, memb, wt, mbp);
    mgemm01_kernel<<<352, 512, 0, stream>>>(
        xb, memb, wt, qb, kb, vb, rel_table, rel_idxs);
    attn5_kernel<<<dim3(16, 16, 2), 256, 0, stream>>>(qb, kb, vb, mbp, aob);
    // last dispatch: out-projection (z=0) + new_mem copy (z=1)
    mgemm2_kernel<<<dim3(8, 32, 2), 256, 0, stream>>>(
        aob, wt + 3 * M1, out, bo, x, out + (size_t)2048 * 1024);
}

// Round 4
// 329.077 us; speedup vs baseline: 1.0209x; 1.0209x over previous
//
#include <hip/hip_runtime.h>
#include <float.h>

#define NQ    1024
#define JTOT  5120
#define MEML  4096
#define SCL2  0.18033688011112042f   /* 0.125 * log2(e) */

typedef __attribute__((ext_vector_type(8))) short bf16x8;
typedef __attribute__((ext_vector_type(8))) unsigned short ush8;
typedef __attribute__((ext_vector_type(4))) unsigned short ush4;
typedef __attribute__((ext_vector_type(4))) float f32x4;

static __device__ __forceinline__ unsigned short f2bf(float x) {
    union { float f; unsigned u; } v; v.f = x;
    unsigned r = (v.u + 0x7fffu + ((v.u >> 16) & 1u)) >> 16;   // RNE
    return (unsigned short)r;
}
// pack trunc-bf16(f0) (low) | trunc-bf16(f1) (high)
static __device__ __forceinline__ unsigned pack2(float f0, float f1) {
    union { float f; unsigned u; } a, b; a.f = f1; b.f = f0;
    return __builtin_amdgcn_perm(a.u, b.u, 0x07060302u);
}

static __device__ __forceinline__ void gld16(const void* g, void* l) {
    __builtin_amdgcn_global_load_lds(
        (const __attribute__((address_space(1))) unsigned int*)g,
        (__attribute__((address_space(3))) unsigned int*)l, 16, 0, 0);
}

// ---------------------------------------------------------------------------
// prep: one launch. blocks [0,1024): x->bf16; [1024,5120): mem->bf16;
// [5120,5160): mask->bias; [5160,9256): W transpose.
// (Writes NO final outputs — early-graph output writes get clobbered by the
// harness re-poison; new_mem is written by the LAST dispatch. R6 post-mortem.)
// ---------------------------------------------------------------------------
__global__ __launch_bounds__(256)
void prep_kernel(const float* __restrict__ x, const float* __restrict__ mem,
                 const unsigned char* __restrict__ mask,
                 const float* __restrict__ W0, const float* __restrict__ W1,
                 const float* __restrict__ W2, const float* __restrict__ W3,
                 unsigned short* __restrict__ xb, unsigned short* __restrict__ memb,
                 unsigned short* __restrict__ wt, float* __restrict__ mbp)
{
    __shared__ float Ts[32][33];
    const int bid = blockIdx.x;
    const int t   = threadIdx.x;
    if (bid < 5120) {
        const float* src = (bid < 1024) ? x : mem;
        unsigned short* dst = (bid < 1024) ? xb : memb;
        const size_t i = (size_t)((bid < 1024) ? bid : bid - 1024) * 2048 + t * 8;
        float4 a = *(const float4*)(src + i);
        float4 b = *(const float4*)(src + i + 4);
        ush8 o;
        o[0] = f2bf(a.x); o[1] = f2bf(a.y); o[2] = f2bf(a.z); o[3] = f2bf(a.w);
        o[4] = f2bf(b.x); o[5] = f2bf(b.y); o[6] = f2bf(b.z); o[7] = f2bf(b.w);
        *(ush8*)(dst + i) = o;
    } else if (bid < 5160) {
        const int i = (bid - 5120) * 256 + t;
        mbp[i] = mask[i] ? -1.0e30f : 0.0f;
    } else {
        const int idx = bid - 5160;
        const int z   = idx >> 10;
        const int rem = idx & 1023;
        const float* W = (z == 0) ? W0 : (z == 1) ? W1 : (z == 2) ? W2 : W3;
        unsigned short* D = wt + (size_t)z * 1024 * 1024;
        const int n0 = (rem & 31) * 32, k0 = (rem >> 5) * 32;
        const int tr = t >> 3, tc = (t & 7) * 4;
        float4 v = *(const float4*)(W + (size_t)(k0 + tr) * 1024 + n0 + tc);
        Ts[tr][tc + 0] = v.x; Ts[tr][tc + 1] = v.y;
        Ts[tr][tc + 2] = v.z; Ts[tr][tc + 3] = v.w;
        __syncthreads();
        ush4 o;
        o[0] = f2bf(Ts[tc + 0][tr]); o[1] = f2bf(Ts[tc + 1][tr]);
        o[2] = f2bf(Ts[tc + 2][tr]); o[3] = f2bf(Ts[tc + 3][tr]);
        *(ush4*)(D + (size_t)(n0 + tr) * 1024 + k0 + tc) = o;
    }
}

// ---------------------------------------------------------------------------
// Merged q/k/v GEMM — 256x256 tile, BK=64, 8-wave (2Mx4N), phased schedule.
// blocks [0,96) = x @ {Wq,Wk,Wv}; [96,352) = mem @ {Wk,Wv}.
//
// R3/R4: LDS split into SIX DISTINCT __shared__ objects (A1R0/A2R0/A1R1/A2R1,
// Bf0/Bf1), selected per call site (stage lambdas take the dest array — after
// inlining the pointer folds to the specific global, keeping object-granular
// alias info). Rationale: SIInsertWaitcnts tracks global_load_lds as LDS-DMA
// stores and inserts its own vmcnt waits before any may-aliasing ds_read
// (inline-asm waitcnts are invisible to it). With Al[2][..]/Bl[2][..] single
// objects, AA pins each phase's frag reads to the MOST RECENT DMA (~1 phase
// earlier) -> near-drain every phase (R1=R2=123us, MfmaUtil 15%). With
// per-region objects, the nearest same-object DMA is >= 4 phases upstream ->
// the compiler's counted wait is free.
// A-row remap keeps row&7, so the XOR swizzle is unchanged:
//   A1R_p: global rows [0,64) -> inner [0,64); [128,192) -> inner [64,128)
//   A2R_p: global rows [64,128) -> inner [0,64); [192,256) -> inner [64,128)
// Phase schedule (per K-step t, buf p):
//   top: 8 ds_read B-frags (Bf_p)
//   ph0: reads A1R_p m0-1 | stage A2(t+1 -> A2R_{p^1})
//   ph1: reads A1R_p m2-3 | stage B0(t+2 -> Bf_p rows 0-127)
//   ph2: reads A2R_p m4-5 | stage A1(t+2 -> A1R_p)
//   ph3: reads A2R_p m6-7 | stage B1(t+2 -> Bf_p rows 128-255); vmcnt(6)
// Each phase: reads+stage -> barrier -> lgkmcnt(0)+sched_barrier -> 16 MFMA
// -> [vmcnt @ph3] -> barrier. Every region's reads drain (lgkmcnt(0)) one
// full barrier before the stage that overwrites that region issues.
// ---------------------------------------------------------------------------
__global__ __launch_bounds__(512, 2)
void mgemm01_kernel(const unsigned short* __restrict__ xb,
                    const unsigned short* __restrict__ memb,
                    const unsigned short* __restrict__ wt,
                    unsigned short* __restrict__ Qb, unsigned short* __restrict__ Kb,
                    unsigned short* __restrict__ Vb,
                    const float* __restrict__ rel_table, const int* __restrict__ rel_idxs)
{
    __shared__ unsigned short A1R0[128 * 64], A2R0[128 * 64];
    __shared__ unsigned short A1R1[128 * 64], A2R1[128 * 64];
    __shared__ unsigned short Bf0[256 * 64],  Bf1[256 * 64];

    const int t    = threadIdx.x;
    const int lane = t & 63;
    const int w    = t >> 6;          // 0..7
    const int wr   = w >> 2;          // 0..1  (M half)
    const int wc   = w & 3;           // 0..3  (N quarter)
    const int l15  = lane & 15;
    const int quad = lane >> 4;
    const int l7   = l15 & 7;
    const int srow = lane >> 3;                 // staging row within 8-row group
    const int scol = ((lane & 7) ^ srow) << 3;  // pre-swizzled source chunk

    int bid = blockIdx.x;
    int mode, bx, by;
    if (bid < 96) { mode = 0; bx = bid % 12; by = bid / 12; }
    else          { bid -= 96; mode = 1; bx = bid & 7; by = bid >> 3; }
    const int mat = bx >> 2;
    const int n0  = (bx & 3) << 8;
    const int m0  = by << 8;
    const unsigned short* Ag = (mode == 0) ? xb : memb;
    const unsigned short* Bg = wt + (size_t)((mode == 0) ? mat : mat + 1) * 1024 * 1024;

    const size_t abase = (size_t)(m0 + srow) * 1024 + scol;
    const size_t bbase = (size_t)(n0 + srow) * 1024 + scol;

    // stage units: 2 gld16/wave each (vmcnt counts instructions: 1 unit = 2).
    // Dest array passed per call site -> folds to a distinct __shared__ object.
    auto stgB0 = [&](unsigned short* BO, int kt) {    // B rows [0,128)
        const int kb = kt << 6, r0 = w * 16;
        gld16(Bg + bbase + (size_t)r0 * 1024 + kb,       BO + r0 * 64);
        gld16(Bg + bbase + (size_t)(r0 + 8) * 1024 + kb, BO + (r0 + 8) * 64);
    };
    auto stgB1 = [&](unsigned short* BO, int kt) {    // B rows [128,256)
        const int kb = kt << 6, r0 = 128 + w * 16;
        gld16(Bg + bbase + (size_t)r0 * 1024 + kb,       BO + r0 * 64);
        gld16(Bg + bbase + (size_t)(r0 + 8) * 1024 + kb, BO + (r0 + 8) * 64);
    };
    auto stgA1 = [&](unsigned short* AO, int kt) {    // A rows [0,64) u [128,192)
        const int kb = kt << 6, r0 = w * 8;
        gld16(Ag + abase + (size_t)r0 * 1024 + kb,         AO + r0 * 64);
        gld16(Ag + abase + (size_t)(128 + r0) * 1024 + kb, AO + (64 + r0) * 64);
    };
    auto stgA2 = [&](unsigned short* AO, int kt) {    // A rows [64,128) u [192,256)
        const int kb = kt << 6, r0 = w * 8;
        gld16(Ag + abase + (size_t)(64 + r0) * 1024 + kb,  AO + r0 * 64);
        gld16(Ag + abase + (size_t)(192 + r0) * 1024 + kb, AO + (64 + r0) * 64);
    };

    f32x4 acc[8][4];
    #pragma unroll
    for (int i = 0; i < 8; i++)
        #pragma unroll
        for (int j = 0; j < 4; j++) acc[i][j] = (f32x4){0.f, 0.f, 0.f, 0.f};

    // prologue: tile0 complete (4 units) + tile1 {B0,A1,B1} = 14 loads;
    // vmcnt(6) retires the oldest 8 = all of tile0.
    stgB0(Bf0, 0); stgB1(Bf0, 0); stgA1(A1R0, 0); stgA2(A2R0, 0);
    stgB0(Bf1, 1); stgA1(A1R1, 1); stgB1(Bf1, 1);
    asm volatile("s_waitcnt vmcnt(6)");
    __builtin_amdgcn_s_barrier();

    bf16x8 bfr[4][2];

#define PHASE(AO, MB, STAGE, VMW)                                                  \
    {                                                                              \
        const int Ra0 = (wr * 64 + ((MB) & 3) * 16 + l15) * 64;                    \
        const int Ra1 = Ra0 + 16 * 64;                                             \
        const bf16x8 a0 = *(const bf16x8*)&AO[Ra0 + ((quad ^ l7) << 3)];           \
        const bf16x8 a1 = *(const bf16x8*)&AO[Ra0 + (((4 | quad) ^ l7) << 3)];     \
        const bf16x8 a2 = *(const bf16x8*)&AO[Ra1 + ((quad ^ l7) << 3)];           \
        const bf16x8 a3 = *(const bf16x8*)&AO[Ra1 + (((4 | quad) ^ l7) << 3)];     \
        STAGE;                                                                     \
        __builtin_amdgcn_s_barrier();                                              \
        asm volatile("s_waitcnt lgkmcnt(0)");                                      \
        __builtin_amdgcn_sched_barrier(0);                                         \
        __builtin_amdgcn_s_setprio(1);                                             \
        _Pragma("unroll")                                                          \
        for (int n = 0; n < 4; n++) {                                              \
            acc[(MB)][n]     = __builtin_amdgcn_mfma_f32_16x16x32_bf16(a0, bfr[n][0], acc[(MB)][n], 0, 0, 0);     \
            acc[(MB)][n]     = __builtin_amdgcn_mfma_f32_16x16x32_bf16(a1, bfr[n][1], acc[(MB)][n], 0, 0, 0);     \
            acc[(MB) + 1][n] = __builtin_amdgcn_mfma_f32_16x16x32_bf16(a2, bfr[n][0], acc[(MB) + 1][n], 0, 0, 0); \
            acc[(MB) + 1][n] = __builtin_amdgcn_mfma_f32_16x16x32_bf16(a3, bfr[n][1], acc[(MB) + 1][n], 0, 0, 0); \
        }                                                                          \
        __builtin_amdgcn_s_setprio(0);                                             \
        VMW;                                                                       \
        __builtin_amdgcn_s_barrier();                                              \
    }

#define KSTEP(A1O, A2O, BO, S0, S1, S2, S3, VMW)                                   \
    {                                                                              \
        _Pragma("unroll")                                                          \
        for (int n = 0; n < 4; n++) {                                              \
            const int Rb = (wc * 64 + n * 16 + l15) * 64;                          \
            bfr[n][0] = *(const bf16x8*)&BO[Rb + ((quad ^ l7) << 3)];              \
            bfr[n][1] = *(const bf16x8*)&BO[Rb + (((4 | quad) ^ l7) << 3)];        \
        }                                                                          \
        PHASE(A1O, 0, S0, (void)0)                                                 \
        PHASE(A1O, 2, S1, (void)0)                                                 \
        PHASE(A2O, 4, S2, (void)0)                                                 \
        PHASE(A2O, 6, S3, VMW)                                                     \
    }

    // main loop: K = 1024 -> 16 K-tiles; bodies textual per buffer parity.
    for (int e = 0; e < 14; e += 2) {
        KSTEP(A1R0, A2R0, Bf0,
              stgA2(A2R1, e + 1),
              stgB0(Bf0, e + 2),
              stgA1(A1R0, e + 2),
              stgB1(Bf0, e + 2),
              asm volatile("s_waitcnt vmcnt(6)"))
        KSTEP(A1R1, A2R1, Bf1,
              stgA2(A2R0, e + 2),
              stgB0(Bf1, e + 3),
              stgA1(A1R1, e + 3),
              stgB1(Bf1, e + 3),
              asm volatile("s_waitcnt vmcnt(6)"))
    }
    // tk = 14: finish tile15's staging (A2 only), then drain.
    KSTEP(A1R0, A2R0, Bf0, stgA2(A2R1, 15), (void)0, (void)0, (void)0,
          asm volatile("s_waitcnt vmcnt(0)"))
    // tk = 15: pure compute.
    KSTEP(A1R1, A2R1, Bf1, (void)0, (void)0, (void)0, (void)0, (void)0)

#undef KSTEP
#undef PHASE

    // epilogue — identical routing to the verified 128² version, 8x4 fragments.
    const bool isQ = (mode == 0) && (mat == 0);
    const bool isK = (mode == 0) ? (mat == 1) : (mat == 0);
    if (!isQ && !isK) {                              // V path
        #pragma unroll
        for (int m = 0; m < 8; m++) {
            const int r0 = m0 + wr * 128 + m * 16 + quad * 4;
            const int bb = (mode == 0) ? (r0 >> 10) : (r0 >> 12);
            const int j0 = (mode == 0) ? 4096 + (r0 & 1023) : (r0 & 4095);
            #pragma unroll
            for (int n = 0; n < 4; n++) {
                const int col = n0 + wc * 64 + n * 16 + l15;
                ush4 o;
                o[0] = f2bf(acc[m][n][0]); o[1] = f2bf(acc[m][n][1]);
                o[2] = f2bf(acc[m][n][2]); o[3] = f2bf(acc[m][n][3]);
                *(ush4*)(Vb + ((size_t)((bb * 16 + (col >> 6)) * 64 + (col & 63))) * JTOT + j0) = o;
            }
        }
    } else {
        #pragma unroll
        for (int m = 0; m < 8; m++)
            #pragma unroll
            for (int reg = 0; reg < 4; reg++) {
                const int r = m0 + wr * 128 + m * 16 + quad * 4 + reg;
                int bb, idx, chunk;
                if (mode == 0) { bb = r >> 10; idx = isK ? 4096 + (r & 1023) : (r & 1023); chunk = 4; }
                else           { bb = r >> 12; idx = r & 4095; chunk = idx >> 10; }
                #pragma unroll
                for (int n = 0; n < 4; n++) {
                    const int col = n0 + wc * 64 + n * 16 + l15;
                    const int hh = col >> 6, dh = col & 63;
                    float v = acc[m][n][reg];
                    if (isK) {
                        v += rel_table[rel_idxs[chunk] * 16 + hh];
                        Kb[((size_t)(bb * 16 + hh) * JTOT + idx) * 64 + dh] = f2bf(v);
                    } else {
                        Qb[((size_t)(bb * 16 + hh) * NQ + idx) * 64 + dh] = f2bf(v);
                    }
                }
            }
    }
}

// ---------------------------------------------------------------------------
// out = ao @ WoT + bo. 64x128 tile, BK=64, swizzled.
// z=1 blocks: copy x -> new_mem (LAST dispatch in graph — survives re-poison).
// ---------------------------------------------------------------------------
__global__ __launch_bounds__(256)
void mgemm2_kernel(const unsigned short* __restrict__ A,
                   const unsigned short* __restrict__ WT,
                   float* __restrict__ outF, const float* __restrict__ bo,
                   const float* __restrict__ x, float* __restrict__ newmem)
{
    __shared__ unsigned short Al[64 * 64];
    __shared__ unsigned short Bl[128 * 64];

    const int t = threadIdx.x;
    if (blockIdx.z == 1) {
        const int blk = blockIdx.y * 8 + blockIdx.x;      // 0..255
        const size_t base = (size_t)blk * 8192 + t * 4;
        #pragma unroll
        for (int i = 0; i < 8; i++)
            *(float4*)(newmem + base + (size_t)i * 1024) =
                *(const float4*)(x + base + (size_t)i * 1024);
        return;
    }

    const int lane = t & 63;
    const int w    = t >> 6;
    const int l15  = lane & 15;
    const int quad = lane >> 4;
    const int l7   = l15 & 7;
    const int n0   = blockIdx.x * 128;
    const int m0   = blockIdx.y * 64;

    f32x4 acc[4][2];
    #pragma unroll
    for (int i = 0; i < 4; i++)
        #pragma unroll
        for (int j = 0; j < 2; j++) acc[i][j] = (f32x4){0.f, 0.f, 0.f, 0.f};

    for (int k0 = 0; k0 < 1024; k0 += 64) {
        __syncthreads();
        #pragma unroll
        for (int it = 0; it < 2; it++) {
            const int lin  = it * 256 + t;
            const int row  = lin >> 3;
            const int colb = ((lin & 7) ^ (row & 7)) * 8;
            gld16(A + (size_t)(m0 + row) * 1024 + k0 + colb,
                  &Al[(size_t)(it * 256 + w * 64) * 8]);
        }
        #pragma unroll
        for (int it = 0; it < 4; it++) {
            const int lin  = it * 256 + t;
            const int row  = lin >> 3;
            const int colb = ((lin & 7) ^ (row & 7)) * 8;
            gld16(WT + (size_t)(n0 + row) * 1024 + k0 + colb,
                  &Bl[(size_t)(it * 256 + w * 64) * 8]);
        }
        __syncthreads();
        bf16x8 af[4][2], bfr[2][2];
        #pragma unroll
        for (int i = 0; i < 4; i++) {
            const int R = i * 16 + l15;
            af[i][0] = *(const bf16x8*)&Al[R * 64 + ((quad ^ l7) << 3)];
            af[i][1] = *(const bf16x8*)&Al[R * 64 + (((4 | quad) ^ l7) << 3)];
        }
        #pragma unroll
        for (int j = 0; j < 2; j++) {
            const int R = w * 32 + j * 16 + l15;
            bfr[j][0] = *(const bf16x8*)&Bl[R * 64 + ((quad ^ l7) << 3)];
            bfr[j][1] = *(const bf16x8*)&Bl[R * 64 + (((4 | quad) ^ l7) << 3)];
        }
        #pragma unroll
        for (int i = 0; i < 4; i++)
            #pragma unroll
            for (int j = 0; j < 2; j++) {
                acc[i][j] = __builtin_amdgcn_mfma_f32_16x16x32_bf16(af[i][0], bfr[j][0], acc[i][j], 0, 0, 0);
                acc[i][j] = __builtin_amdgcn_mfma_f32_16x16x32_bf16(af[i][1], bfr[j][1], acc[i][j], 0, 0, 0);
            }
    }

    #pragma unroll
    for (int i = 0; i < 4; i++)
        #pragma unroll
        for (int reg = 0; reg < 4; reg++) {
            const int r = m0 + i * 16 + quad * 4 + reg;
            #pragma unroll
            for (int j = 0; j < 2; j++) {
                const int col = n0 + w * 32 + j * 16 + l15;
                outF[(size_t)r * 1024 + col] = acc[i][j][reg] + bo[col];
            }
        }
}

// ---------------------------------------------------------------------------
// Flash attention, S^T formulation, 128-key tiles, swizzled 48 KB LDS.
// R9: NO online max — scores are bounded (|s*log2e| << 127, bf16 inputs), so
// softmax = exp2(s)/sum(exp2(s)) directly: per-lane-only loop (fma/exp/add/
// pack), l_i partial per lane, cross-quad reduce ONCE in epilogue.
// exp2 via __builtin_amdgcn_exp2f (bare v_exp_f32, not the ocml precise path).
// ---------------------------------------------------------------------------
__global__ __launch_bounds__(256)
void attn5_kernel(const unsigned short* __restrict__ qh,
                  const unsigned short* __restrict__ kh,
                  const unsigned short* __restrict__ vt,
                  const float* __restrict__ mb,
                  unsigned short* __restrict__ ao)
{
    __shared__ unsigned short Ks[128 * 64];   // [key][dh] swizzled (8-unit rows)
    __shared__ unsigned short Vs[64 * 128];   // [dh][key] swizzled (16-unit rows)
    __shared__ unsigned short Ps[64 * 128];   // [q][key]  swizzled (16-unit rows)

    const int t    = threadIdx.x;
    const int lane = t & 63;
    const int w    = t >> 6;
    const int l15  = lane & 15;
    const int quad = lane >> 4;
    const int l7   = l15 & 7;
    const int qt   = blockIdx.x;
    const int h    = blockIdx.y;
    const int b    = blockIdx.z;
    const int qbase = qt * 64;
    const int qg    = qbase + w * 16 + l15;

    const unsigned short* qrow = qh + (((size_t)(b * 16 + h) * NQ + qg) << 6);
    const bf16x8 bq0 = *(const bf16x8*)(qrow + quad * 8);
    const bf16x8 bq1 = *(const bf16x8*)(qrow + 32 + quad * 8);

    const int krow = t >> 3;
    const int kcol = (t & 7) * 8;
    const int ksw  = ((t & 7) ^ (krow & 7)) * 8;
    const int vrow = t >> 4;
    const int vu   = t & 15;
    const int vcol = vu * 8;
    const int vsw  = ((vu & 8) | ((vu ^ (vrow & 7)) & 7)) * 8;

    const unsigned short* kbase = kh + (((size_t)(b * 16 + h) * JTOT) << 6);
    const unsigned short* vbase = vt + (((size_t)(b * 16 + h)) << 6) * JTOT;
    const float* mbb = mb + b * JTOT;

    f32x4 oa[4];
    #pragma unroll
    for (int mt = 0; mt < 4; mt++) oa[mt] = (f32x4){0.f, 0.f, 0.f, 0.f};
    float l_i = 0.f;                           // per-lane partial (32 keys/tile)

    const int ntp = (qt + 66) >> 1;           // 128-key tiles (padded)

    ush8 kst[4], vst[4];
    #pragma unroll
    for (int p = 0; p < 4; p++)
        kst[p] = *(const ush8*)(kbase + ((size_t)(krow + 32 * p) << 6) + kcol);
    #pragma unroll
    for (int p = 0; p < 4; p++)
        vst[p] = *(const ush8*)(vbase + (size_t)(vrow + 16 * p) * JTOT + vcol);

    for (int jt = 0; jt < ntp; jt++) {
        const int jbase = jt * 128;
        __syncthreads();
        #pragma unroll
        for (int p = 0; p < 4; p++)
            *(ush8*)&Ks[(krow + 32 * p) * 64 + ksw] = kst[p];
        #pragma unroll
        for (int p = 0; p < 4; p++)
            *(ush8*)&Vs[(vrow + 16 * p) * 128 + vsw] = vst[p];
        __syncthreads();

        if (jt + 1 < ntp) {
            const int jb2 = jbase + 128;
            #pragma unroll
            for (int p = 0; p < 4; p++)
                kst[p] = *(const ush8*)(kbase + ((size_t)(jb2 + krow + 32 * p) << 6) + kcol);
            #pragma unroll
            for (int p = 0; p < 4; p++)
                vst[p] = *(const ush8*)(vbase + (size_t)(vrow + 16 * p) * JTOT + jb2 + vcol);
        }

        // St = K.Q^T : 128 keys x 16 q per wave
        f32x4 sa[8];
        #pragma unroll
        for (int mt2 = 0; mt2 < 8; mt2++) {
            const int ra = (mt2 * 16 + l15) * 64;
            const bf16x8 ak0 = *(const bf16x8*)&Ks[ra + ((quad ^ l7) << 3)];
            const bf16x8 ak1 = *(const bf16x8*)&Ks[ra + (((4 | quad) ^ l7) << 3)];
            f32x4 s = (f32x4){0.f, 0.f, 0.f, 0.f};
            s = __builtin_amdgcn_mfma_f32_16x16x32_bf16(ak0, bq0, s, 0, 0, 0);
            s = __builtin_amdgcn_mfma_f32_16x16x32_bf16(ak1, bq1, s, 0, 0, 0);
            sa[mt2] = s;
        }

        // scale (exp2 domain) + key-mask bias
        #pragma unroll
        for (int mt2 = 0; mt2 < 8; mt2++) {
            const float4 mv = *(const float4*)(mbb + jbase + mt2 * 16 + quad * 4);
            sa[mt2][0] = sa[mt2][0] * SCL2 + mv.x;
            sa[mt2][1] = sa[mt2][1] * SCL2 + mv.y;
            sa[mt2][2] = sa[mt2][2] * SCL2 + mv.z;
            sa[mt2][3] = sa[mt2][3] * SCL2 + mv.w;
        }
        // causal (+pad) mask: only the last tile contains the boundary
        if (jt == ntp - 1) {
            const int tl = qg + 4096 - jbase;
            #pragma unroll
            for (int mt2 = 0; mt2 < 8; mt2++)
                #pragma unroll
                for (int r = 0; r < 4; r++)
                    if (mt2 * 16 + quad * 4 + r > tl) sa[mt2][r] = -1.0e30f;
        }

        // softmax numerator: pure per-lane (no max, no cross-lane this tile)
        #pragma unroll
        for (int mt2 = 0; mt2 < 8; mt2++)
            #pragma unroll
            for (int r = 0; r < 4; r++) {
                const float pv = __builtin_amdgcn_exp2f(sa[mt2][r]);
                sa[mt2][r] = pv;
                l_i += pv;
            }

        // P -> Ps[q][key] (uint2 packed, truncation); same-wave rows, no barrier
        const int prow = (w * 16 + l15) * 128;
        #pragma unroll
        for (int mt2 = 0; mt2 < 8; mt2++) {
            const int u  = 2 * mt2 + (quad >> 1);
            const int up = (u & 8) | ((u ^ l7) & 7);
            uint2 pk;
            pk.x = pack2(sa[mt2][0], sa[mt2][1]);
            pk.y = pack2(sa[mt2][2], sa[mt2][3]);
            *(uint2*)&Ps[prow + up * 8 + (quad & 1) * 4] = pk;
        }

        // O^T += V^T.P^T
        #pragma unroll
        for (int s = 0; s < 4; s++) {
            const int u  = quad + 4 * s;
            const int up = (u & 8) | ((u ^ l7) & 7);
            const bf16x8 bp = *(const bf16x8*)&Ps[prow + up * 8];
            #pragma unroll
            for (int mt = 0; mt < 4; mt++) {
                const bf16x8 av = *(const bf16x8*)&Vs[(mt * 16 + l15) * 128 + up * 8];
                oa[mt] = __builtin_amdgcn_mfma_f32_16x16x32_bf16(av, bp, oa[mt], 0, 0, 0);
            }
        }
    }

    // epilogue: cross-quad l reduce (the 4 quads of the same l15 hold disjoint
    // key partials for q=qg), then normalize and store.
    float l = l_i;
    l += __shfl_xor(l, 16);
    l += __shfl_xor(l, 32);
    const float inv = 1.0f / l;
    unsigned short* arow = ao + ((size_t)(b * NQ + qg)) * 1024 + h * 64;
    #pragma unroll
    for (int mt = 0; mt < 4; mt++) {
        ush4 o;
        o[0] = f2bf(oa[mt][0] * inv); o[1] = f2bf(oa[mt][1] * inv);
        o[2] = f2bf(oa[mt][2] * inv); o[3] = f2bf(oa[mt][3] * inv);
        *(ush4*)(arow + mt * 16 + quad * 4) = o;
    }
}

// ---------------------------------------------------------------------------
extern "C" void kernel_launch(void* const* d_in, const int* in_sizes, int n_in,
                              void* d_out, int out_size, void* d_ws, size_t ws_size,
                              hipStream_t stream)
{
    const float* x        = (const float*)d_in[0];
    const float* mem      = (const float*)d_in[1];
    const unsigned char* mask = (const unsigned char*)d_in[2];
    const int*   rel_idxs = (const int*)d_in[3];
    const float* Wq       = (const float*)d_in[4];
    const float* Wk       = (const float*)d_in[5];
    const float* Wv       = (const float*)d_in[6];
    const float* Wo       = (const float*)d_in[7];
    const float* bo       = (const float*)d_in[8];
    const float* rel_table= (const float*)d_in[9];

    float* out = (float*)d_out;
    const size_t M1 = (size_t)1024 * 1024;
    unsigned short* xb   = (unsigned short*)d_ws;   //  2M
    unsigned short* memb = xb   + 2 * M1;           //  8M
    unsigned short* wt   = memb + 8 * M1;           //  4M
    unsigned short* qb   = wt   + 4 * M1;           //  2M  qh[b][h][q][dh]
    unsigned short* kb   = qb   + 2 * M1;           // 10M  kh[b][h][j][dh]
    unsigned short* vb   = kb   + 10 * M1;          // 10M  vt[b][h][dh][j]
    unsigned short* aob  = vb   + 10 * M1;          //  2M
    float* mbp = (float*)(aob + 2 * M1);            // 10240 floats

    prep_kernel<<<9256, 256, 0, stream>>>(
        x, mem, mask, Wq, Wk, Wv, Wo, xb, memb, wt, mbp);
    mgemm01_kernel<<<352, 512, 0, stream>>>(
        xb, memb, wt, qb, kb, vb, rel_table, rel_idxs);
    attn5_kernel<<<dim3(16, 16, 2), 256, 0, stream>>>(qb, kb, vb, mbp, aob);
    // last dispatch: out-projection (z=0) + new_mem copy (z=1)
    mgemm2_kernel<<<dim3(8, 32, 2), 256, 0, stream>>>(
        aob, wt + 3 * M1, out, bo, x, out + (size_t)2048 * 1024);
}

// Round 6
// 304.020 us; speedup vs baseline: 1.1050x; 1.0824x over previous
//
#include <hip/hip_runtime.h>
#include <float.h>

#define NQ    1024
#define JTOT  5120
#define MEML  4096
#define SCL2  0.18033688011112042f   /* 0.125 * log2(e) */

typedef __attribute__((ext_vector_type(8))) short bf16x8;
typedef __attribute__((ext_vector_type(8))) unsigned short ush8;
typedef __attribute__((ext_vector_type(4))) unsigned short ush4;
typedef __attribute__((ext_vector_type(4))) float f32x4;

static __device__ __forceinline__ unsigned short f2bf(float x) {
    union { float f; unsigned u; } v; v.f = x;
    unsigned r = (v.u + 0x7fffu + ((v.u >> 16) & 1u)) >> 16;   // RNE
    return (unsigned short)r;
}
// pack trunc-bf16(f0) (low) | trunc-bf16(f1) (high)
static __device__ __forceinline__ unsigned pack2(float f0, float f1) {
    union { float f; unsigned u; } a, b; a.f = f1; b.f = f0;
    return __builtin_amdgcn_perm(a.u, b.u, 0x07060302u);
}

static __device__ __forceinline__ void gld16(const void* g, void* l) {
    __builtin_amdgcn_global_load_lds(
        (const __attribute__((address_space(1))) unsigned int*)g,
        (__attribute__((address_space(3))) unsigned int*)l, 16, 0, 0);
}

// ---------------------------------------------------------------------------
// prep: one launch. blocks [0,1024): x->bf16; [1024,5120): mem->bf16;
// [5120,5160): mask->bias; [5160,9256): W transpose.
// (Writes NO final outputs — early-graph output writes get clobbered by the
// harness re-poison; new_mem is written by the LAST dispatch. R6 post-mortem.)
// ---------------------------------------------------------------------------
__global__ __launch_bounds__(256)
void prep_kernel(const float* __restrict__ x, const float* __restrict__ mem,
                 const unsigned char* __restrict__ mask,
                 const float* __restrict__ W0, const float* __restrict__ W1,
                 const float* __restrict__ W2, const float* __restrict__ W3,
                 unsigned short* __restrict__ xb, unsigned short* __restrict__ memb,
                 unsigned short* __restrict__ wt, float* __restrict__ mbp)
{
    __shared__ float Ts[32][33];
    const int bid = blockIdx.x;
    const int t   = threadIdx.x;
    if (bid < 5120) {
        const float* src = (bid < 1024) ? x : mem;
        unsigned short* dst = (bid < 1024) ? xb : memb;
        const size_t i = (size_t)((bid < 1024) ? bid : bid - 1024) * 2048 + t * 8;
        float4 a = *(const float4*)(src + i);
        float4 b = *(const float4*)(src + i + 4);
        ush8 o;
        o[0] = f2bf(a.x); o[1] = f2bf(a.y); o[2] = f2bf(a.z); o[3] = f2bf(a.w);
        o[4] = f2bf(b.x); o[5] = f2bf(b.y); o[6] = f2bf(b.z); o[7] = f2bf(b.w);
        *(ush8*)(dst + i) = o;
    } else if (bid < 5160) {
        const int i = (bid - 5120) * 256 + t;
        mbp[i] = mask[i] ? -1.0e30f : 0.0f;
    } else {
        const int idx = bid - 5160;
        const int z   = idx >> 10;
        const int rem = idx & 1023;
        const float* W = (z == 0) ? W0 : (z == 1) ? W1 : (z == 2) ? W2 : W3;
        unsigned short* D = wt + (size_t)z * 1024 * 1024;
        const int n0 = (rem & 31) * 32, k0 = (rem >> 5) * 32;
        const int tr = t >> 3, tc = (t & 7) * 4;
        float4 v = *(const float4*)(W + (size_t)(k0 + tr) * 1024 + n0 + tc);
        Ts[tr][tc + 0] = v.x; Ts[tr][tc + 1] = v.y;
        Ts[tr][tc + 2] = v.z; Ts[tr][tc + 3] = v.w;
        __syncthreads();
        ush4 o;
        o[0] = f2bf(Ts[tc + 0][tr]); o[1] = f2bf(Ts[tc + 1][tr]);
        o[2] = f2bf(Ts[tc + 2][tr]); o[3] = f2bf(Ts[tc + 3][tr]);
        *(ush4*)(D + (size_t)(n0 + tr) * 1024 + k0 + tc) = o;
    }
}

// ---------------------------------------------------------------------------
// Merged q/k/v GEMM — 256x256 tile, BK=64, 8-wave (2Mx4N), phased schedule.
// blocks [0,96) = x @ {Wq,Wk,Wv}; [96,352) = mem @ {Wk,Wv}.
//
// R5/R6: chunked XCD swizzle (T1). Counter evidence: FETCH 91 MB vs 16 MB
// unique input in BOTH the 128² (R0) and 256² (R4) structures, equal times —
// L2-miss traffic-bound, not sync-structure-bound. Old mode1 map (bx=p&7,
// XCD=p%8) gave each XCD one B panel but ALL 32 A slices -> every XCD
// streamed the whole 16 MB memb (no inter-block A sharing). New map
// (XCD = bid%8 assumed):
//   mode0: XCD c gets logical l in [12c,12c+12), by-fastest (l=bx*8+by):
//          ~1.5 B panels + xb (2 MB) per XCD -> ~3.5 MB, L2-fits.
//   mode1: XCD c gets an (8 bx x 4 by) region: all 8 B panels (4 MB, hot,
//          L2-resident) + 4 A slices (2 MB, each shared concurrently by the
//          8 blocks of a bx-octet). A fetched ~once chip-wide instead of 8x.
// Sync structure unchanged from R4 (six LDS objects, 4-phase counted-vmcnt).
// ---------------------------------------------------------------------------
__global__ __launch_bounds__(512, 2)
void mgemm01_kernel(const unsigned short* __restrict__ xb,
                    const unsigned short* __restrict__ memb,
                    const unsigned short* __restrict__ wt,
                    unsigned short* __restrict__ Qb, unsigned short* __restrict__ Kb,
                    unsigned short* __restrict__ Vb,
                    const float* __restrict__ rel_table, const int* __restrict__ rel_idxs)
{
    __shared__ unsigned short A1R0[128 * 64], A2R0[128 * 64];
    __shared__ unsigned short A1R1[128 * 64], A2R1[128 * 64];
    __shared__ unsigned short Bf0[256 * 64],  Bf1[256 * 64];

    const int t    = threadIdx.x;
    const int lane = t & 63;
    const int w    = t >> 6;          // 0..7
    const int wr   = w >> 2;          // 0..1  (M half)
    const int wc   = w & 3;           // 0..3  (N quarter)
    const int l15  = lane & 15;
    const int quad = lane >> 4;
    const int l7   = l15 & 7;
    const int srow = lane >> 3;                 // staging row within 8-row group
    const int scol = ((lane & 7) ^ srow) << 3;  // pre-swizzled source chunk

    const int bid = blockIdx.x;
    int mode, bx, by;
    if (bid < 96) {
        mode = 0;
        const int l = (bid & 7) * 12 + (bid >> 3);   // XCD-contiguous logical id
        bx = l >> 3;                                 // 0..11 (by-fastest: share bx)
        by = l & 7;                                  // 0..7
    } else {
        mode = 1;
        const int p   = bid - 96;                    // 96 % 8 == 0 -> p%8 == bid%8
        const int xcd = p & 7;
        const int i   = p >> 3;                      // 0..31 within XCD
        bx = i & 7;                                  // all 8 B panels per XCD
        by = (xcd << 2) + (i >> 3);                  // 4 contiguous A slices per XCD
    }
    const int mat = bx >> 2;
    const int n0  = (bx & 3) << 8;
    const int m0  = by << 8;
    const unsigned short* Ag = (mode == 0) ? xb : memb;
    const unsigned short* Bg = wt + (size_t)((mode == 0) ? mat : mat + 1) * 1024 * 1024;

    const size_t abase = (size_t)(m0 + srow) * 1024 + scol;
    const size_t bbase = (size_t)(n0 + srow) * 1024 + scol;

    // stage units: 2 gld16/wave each (vmcnt counts instructions: 1 unit = 2).
    // Dest array passed per call site -> folds to a distinct __shared__ object.
    auto stgB0 = [&](unsigned short* BO, int kt) {    // B rows [0,128)
        const int kb = kt << 6, r0 = w * 16;
        gld16(Bg + bbase + (size_t)r0 * 1024 + kb,       BO + r0 * 64);
        gld16(Bg + bbase + (size_t)(r0 + 8) * 1024 + kb, BO + (r0 + 8) * 64);
    };
    auto stgB1 = [&](unsigned short* BO, int kt) {    // B rows [128,256)
        const int kb = kt << 6, r0 = 128 + w * 16;
        gld16(Bg + bbase + (size_t)r0 * 1024 + kb,       BO + r0 * 64);
        gld16(Bg + bbase + (size_t)(r0 + 8) * 1024 + kb, BO + (r0 + 8) * 64);
    };
    auto stgA1 = [&](unsigned short* AO, int kt) {    // A rows [0,64) u [128,192)
        const int kb = kt << 6, r0 = w * 8;
        gld16(Ag + abase + (size_t)r0 * 1024 + kb,         AO + r0 * 64);
        gld16(Ag + abase + (size_t)(128 + r0) * 1024 + kb, AO + (64 + r0) * 64);
    };
    auto stgA2 = [&](unsigned short* AO, int kt) {    // A rows [64,128) u [192,256)
        const int kb = kt << 6, r0 = w * 8;
        gld16(Ag + abase + (size_t)(64 + r0) * 1024 + kb,  AO + r0 * 64);
        gld16(Ag + abase + (size_t)(192 + r0) * 1024 + kb, AO + (64 + r0) * 64);
    };

    f32x4 acc[8][4];
    #pragma unroll
    for (int i = 0; i < 8; i++)
        #pragma unroll
        for (int j = 0; j < 4; j++) acc[i][j] = (f32x4){0.f, 0.f, 0.f, 0.f};

    // prologue: tile0 complete (4 units) + tile1 {B0,A1,B1} = 14 loads;
    // vmcnt(6) retires the oldest 8 = all of tile0.
    stgB0(Bf0, 0); stgB1(Bf0, 0); stgA1(A1R0, 0); stgA2(A2R0, 0);
    stgB0(Bf1, 1); stgA1(A1R1, 1); stgB1(Bf1, 1);
    asm volatile("s_waitcnt vmcnt(6)");
    __builtin_amdgcn_s_barrier();

    bf16x8 bfr[4][2];

#define PHASE(AO, MB, STAGE, VMW)                                                  \
    {                                                                              \
        const int Ra0 = (wr * 64 + ((MB) & 3) * 16 + l15) * 64;                    \
        const int Ra1 = Ra0 + 16 * 64;                                             \
        const bf16x8 a0 = *(const bf16x8*)&AO[Ra0 + ((quad ^ l7) << 3)];           \
        const bf16x8 a1 = *(const bf16x8*)&AO[Ra0 + (((4 | quad) ^ l7) << 3)];     \
        const bf16x8 a2 = *(const bf16x8*)&AO[Ra1 + ((quad ^ l7) << 3)];           \
        const bf16x8 a3 = *(const bf16x8*)&AO[Ra1 + (((4 | quad) ^ l7) << 3)];     \
        STAGE;                                                                     \
        __builtin_amdgcn_s_barrier();                                              \
        asm volatile("s_waitcnt lgkmcnt(0)");                                      \
        __builtin_amdgcn_sched_barrier(0);                                         \
        __builtin_amdgcn_s_setprio(1);                                             \
        _Pragma("unroll")                                                          \
        for (int n = 0; n < 4; n++) {                                              \
            acc[(MB)][n]     = __builtin_amdgcn_mfma_f32_16x16x32_bf16(a0, bfr[n][0], acc[(MB)][n], 0, 0, 0);     \
            acc[(MB)][n]     = __builtin_amdgcn_mfma_f32_16x16x32_bf16(a1, bfr[n][1], acc[(MB)][n], 0, 0, 0);     \
            acc[(MB) + 1][n] = __builtin_amdgcn_mfma_f32_16x16x32_bf16(a2, bfr[n][0], acc[(MB) + 1][n], 0, 0, 0); \
            acc[(MB) + 1][n] = __builtin_amdgcn_mfma_f32_16x16x32_bf16(a3, bfr[n][1], acc[(MB) + 1][n], 0, 0, 0); \
        }                                                                          \
        __builtin_amdgcn_s_setprio(0);                                             \
        VMW;                                                                       \
        __builtin_amdgcn_s_barrier();                                              \
    }

#define KSTEP(A1O, A2O, BO, S0, S1, S2, S3, VMW)                                   \
    {                                                                              \
        _Pragma("unroll")                                                          \
        for (int n = 0; n < 4; n++) {                                              \
            const int Rb = (wc * 64 + n * 16 + l15) * 64;                          \
            bfr[n][0] = *(const bf16x8*)&BO[Rb + ((quad ^ l7) << 3)];              \
            bfr[n][1] = *(const bf16x8*)&BO[Rb + (((4 | quad) ^ l7) << 3)];        \
        }                                                                          \
        PHASE(A1O, 0, S0, (void)0)                                                 \
        PHASE(A1O, 2, S1, (void)0)                                                 \
        PHASE(A2O, 4, S2, (void)0)                                                 \
        PHASE(A2O, 6, S3, VMW)                                                     \
    }

    // main loop: K = 1024 -> 16 K-tiles; bodies textual per buffer parity.
    for (int e = 0; e < 14; e += 2) {
        KSTEP(A1R0, A2R0, Bf0,
              stgA2(A2R1, e + 1),
              stgB0(Bf0, e + 2),
              stgA1(A1R0, e + 2),
              stgB1(Bf0, e + 2),
              asm volatile("s_waitcnt vmcnt(6)"))
        KSTEP(A1R1, A2R1, Bf1,
              stgA2(A2R0, e + 2),
              stgB0(Bf1, e + 3),
              stgA1(A1R1, e + 3),
              stgB1(Bf1, e + 3),
              asm volatile("s_waitcnt vmcnt(6)"))
    }
    // tk = 14: finish tile15's staging (A2 only), then drain.
    KSTEP(A1R0, A2R0, Bf0, stgA2(A2R1, 15), (void)0, (void)0, (void)0,
          asm volatile("s_waitcnt vmcnt(0)"))
    // tk = 15: pure compute.
    KSTEP(A1R1, A2R1, Bf1, (void)0, (void)0, (void)0, (void)0, (void)0)

#undef KSTEP
#undef PHASE

    // epilogue — identical routing to the verified 128² version, 8x4 fragments.
    const bool isQ = (mode == 0) && (mat == 0);
    const bool isK = (mode == 0) ? (mat == 1) : (mat == 0);
    if (!isQ && !isK) {                              // V path
        #pragma unroll
        for (int m = 0; m < 8; m++) {
            const int r0 = m0 + wr * 128 + m * 16 + quad * 4;
            const int bb = (mode == 0) ? (r0 >> 10) : (r0 >> 12);
            const int j0 = (mode == 0) ? 4096 + (r0 & 1023) : (r0 & 4095);
            #pragma unroll
            for (int n = 0; n < 4; n++) {
                const int col = n0 + wc * 64 + n * 16 + l15;
                ush4 o;
                o[0] = f2bf(acc[m][n][0]); o[1] = f2bf(acc[m][n][1]);
                o[2] = f2bf(acc[m][n][2]); o[3] = f2bf(acc[m][n][3]);
                *(ush4*)(Vb + ((size_t)((bb * 16 + (col >> 6)) * 64 + (col & 63))) * JTOT + j0) = o;
            }
        }
    } else {
        #pragma unroll
        for (int m = 0; m < 8; m++)
            #pragma unroll
            for (int reg = 0; reg < 4; reg++) {
                const int r = m0 + wr * 128 + m * 16 + quad * 4 + reg;
                int bb, idx, chunk;
                if (mode == 0) { bb = r >> 10; idx = isK ? 4096 + (r & 1023) : (r & 1023); chunk = 4; }
                else           { bb = r >> 12; idx = r & 4095; chunk = idx >> 10; }
                #pragma unroll
                for (int n = 0; n < 4; n++) {
                    const int col = n0 + wc * 64 + n * 16 + l15;
                    const int hh = col >> 6, dh = col & 63;
                    float v = acc[m][n][reg];
                    if (isK) {
                        v += rel_table[rel_idxs[chunk] * 16 + hh];
                        Kb[((size_t)(bb * 16 + hh) * JTOT + idx) * 64 + dh] = f2bf(v);
                    } else {
                        Qb[((size_t)(bb * 16 + hh) * NQ + idx) * 64 + dh] = f2bf(v);
                    }
                }
            }
    }
}

// ---------------------------------------------------------------------------
// out = ao @ WoT + bo. 64x128 tile, BK=64, swizzled.
// z=1 blocks: copy x -> new_mem (LAST dispatch in graph — survives re-poison).
// ---------------------------------------------------------------------------
__global__ __launch_bounds__(256)
void mgemm2_kernel(const unsigned short* __restrict__ A,
                   const unsigned short* __restrict__ WT,
                   float* __restrict__ outF, const float* __restrict__ bo,
                   const float* __restrict__ x, float* __restrict__ newmem)
{
    __shared__ unsigned short Al[64 * 64];
    __shared__ unsigned short Bl[128 * 64];

    const int t = threadIdx.x;
    if (blockIdx.z == 1) {
        const int blk = blockIdx.y * 8 + blockIdx.x;      // 0..255
        const size_t base = (size_t)blk * 8192 + t * 4;
        #pragma unroll
        for (int i = 0; i < 8; i++)
            *(float4*)(newmem + base + (size_t)i * 1024) =
                *(const float4*)(x + base + (size_t)i * 1024);
        return;
    }

    const int lane = t & 63;
    const int w    = t >> 6;
    const int l15  = lane & 15;
    const int quad = lane >> 4;
    const int l7   = l15 & 7;
    const int n0   = blockIdx.x * 128;
    const int m0   = blockIdx.y * 64;

    f32x4 acc[4][2];
    #pragma unroll
    for (int i = 0; i < 4; i++)
        #pragma unroll
        for (int j = 0; j < 2; j++) acc[i][j] = (f32x4){0.f, 0.f, 0.f, 0.f};

    for (int k0 = 0; k0 < 1024; k0 += 64) {
        __syncthreads();
        #pragma unroll
        for (int it = 0; it < 2; it++) {
            const int lin  = it * 256 + t;
            const int row  = lin >> 3;
            const int colb = ((lin & 7) ^ (row & 7)) * 8;
            gld16(A + (size_t)(m0 + row) * 1024 + k0 + colb,
                  &Al[(size_t)(it * 256 + w * 64) * 8]);
        }
        #pragma unroll
        for (int it = 0; it < 4; it++) {
            const int lin  = it * 256 + t;
            const int row  = lin >> 3;
            const int colb = ((lin & 7) ^ (row & 7)) * 8;
            gld16(WT + (size_t)(n0 + row) * 1024 + k0 + colb,
                  &Bl[(size_t)(it * 256 + w * 64) * 8]);
        }
        __syncthreads();
        bf16x8 af[4][2], bfr[2][2];
        #pragma unroll
        for (int i = 0; i < 4; i++) {
            const int R = i * 16 + l15;
            af[i][0] = *(const bf16x8*)&Al[R * 64 + ((quad ^ l7) << 3)];
            af[i][1] = *(const bf16x8*)&Al[R * 64 + (((4 | quad) ^ l7) << 3)];
        }
        #pragma unroll
        for (int j = 0; j < 2; j++) {
            const int R = w * 32 + j * 16 + l15;
            bfr[j][0] = *(const bf16x8*)&Bl[R * 64 + ((quad ^ l7) << 3)];
            bfr[j][1] = *(const bf16x8*)&Bl[R * 64 + (((4 | quad) ^ l7) << 3)];
        }
        #pragma unroll
        for (int i = 0; i < 4; i++)
            #pragma unroll
            for (int j = 0; j < 2; j++) {
                acc[i][j] = __builtin_amdgcn_mfma_f32_16x16x32_bf16(af[i][0], bfr[j][0], acc[i][j], 0, 0, 0);
                acc[i][j] = __builtin_amdgcn_mfma_f32_16x16x32_bf16(af[i][1], bfr[j][1], acc[i][j], 0, 0, 0);
            }
    }

    #pragma unroll
    for (int i = 0; i < 4; i++)
        #pragma unroll
        for (int reg = 0; reg < 4; reg++) {
            const int r = m0 + i * 16 + quad * 4 + reg;
            #pragma unroll
            for (int j = 0; j < 2; j++) {
                const int col = n0 + w * 32 + j * 16 + l15;
                outF[(size_t)r * 1024 + col] = acc[i][j][reg] + bo[col];
            }
        }
}

// ---------------------------------------------------------------------------
// Flash attention, S^T formulation, 128-key tiles, swizzled 48 KB LDS.
// R9: NO online max — scores are bounded (|s*log2e| << 127, bf16 inputs), so
// softmax = exp2(s)/sum(exp2(s)) directly: per-lane-only loop (fma/exp/add/
// pack), l_i partial per lane, cross-quad reduce ONCE in epilogue.
// exp2 via __builtin_amdgcn_exp2f (bare v_exp_f32, not the ocml precise path).
// R5: s_setprio(1) around the QK^T and PV MFMA clusters (T5; m191 attn +4-7%:
// multi-block-per-CU independent waves — the regime where setprio pays).
// ---------------------------------------------------------------------------
__global__ __launch_bounds__(256)
void attn5_kernel(const unsigned short* __restrict__ qh,
                  const unsigned short* __restrict__ kh,
                  const unsigned short* __restrict__ vt,
                  const float* __restrict__ mb,
                  unsigned short* __restrict__ ao)
{
    __shared__ unsigned short Ks[128 * 64];   // [key][dh] swizzled (8-unit rows)
    __shared__ unsigned short Vs[64 * 128];   // [dh][key] swizzled (16-unit rows)
    __shared__ unsigned short Ps[64 * 128];   // [q][key]  swizzled (16-unit rows)

    const int t    = threadIdx.x;
    const int lane = t & 63;
    const int w    = t >> 6;
    const int l15  = lane & 15;
    const int quad = lane >> 4;
    const int l7   = l15 & 7;
    const int qt   = blockIdx.x;
    const int h    = blockIdx.y;
    const int b    = blockIdx.z;
    const int qbase = qt * 64;
    const int qg    = qbase + w * 16 + l15;

    const unsigned short* qrow = qh + (((size_t)(b * 16 + h) * NQ + qg) << 6);
    const bf16x8 bq0 = *(const bf16x8*)(qrow + quad * 8);
    const bf16x8 bq1 = *(const bf16x8*)(qrow + 32 + quad * 8);

    const int krow = t >> 3;
    const int kcol = (t & 7) * 8;
    const int ksw  = ((t & 7) ^ (krow & 7)) * 8;
    const int vrow = t >> 4;
    const int vu   = t & 15;
    const int vcol = vu * 8;
    const int vsw  = ((vu & 8) | ((vu ^ (vrow & 7)) & 7)) * 8;

    const unsigned short* kbase = kh + (((size_t)(b * 16 + h) * JTOT) << 6);
    const unsigned short* vbase = vt + (((size_t)(b * 16 + h)) << 6) * JTOT;
    const float* mbb = mb + b * JTOT;

    f32x4 oa[4];
    #pragma unroll
    for (int mt = 0; mt < 4; mt++) oa[mt] = (f32x4){0.f, 0.f, 0.f, 0.f};
    float l_i = 0.f;                           // per-lane partial (32 keys/tile)

    const int ntp = (qt + 66) >> 1;           // 128-key tiles (padded)

    ush8 kst[4], vst[4];
    #pragma unroll
    for (int p = 0; p < 4; p++)
        kst[p] = *(const ush8*)(kbase + ((size_t)(krow + 32 * p) << 6) + kcol);
    #pragma unroll
    for (int p = 0; p < 4; p++)
        vst[p] = *(const ush8*)(vbase + (size_t)(vrow + 16 * p) * JTOT + vcol);

    for (int jt = 0; jt < ntp; jt++) {
        const int jbase = jt * 128;
        __syncthreads();
        #pragma unroll
        for (int p = 0; p < 4; p++)
            *(ush8*)&Ks[(krow + 32 * p) * 64 + ksw] = kst[p];
        #pragma unroll
        for (int p = 0; p < 4; p++)
            *(ush8*)&Vs[(vrow + 16 * p) * 128 + vsw] = vst[p];
        __syncthreads();

        if (jt + 1 < ntp) {
            const int jb2 = jbase + 128;
            #pragma unroll
            for (int p = 0; p < 4; p++)
                kst[p] = *(const ush8*)(kbase + ((size_t)(jb2 + krow + 32 * p) << 6) + kcol);
            #pragma unroll
            for (int p = 0; p < 4; p++)
                vst[p] = *(const ush8*)(vbase + (size_t)(vrow + 16 * p) * JTOT + jb2 + vcol);
        }

        // St = K.Q^T : 128 keys x 16 q per wave
        f32x4 sa[8];
        __builtin_amdgcn_s_setprio(1);
        #pragma unroll
        for (int mt2 = 0; mt2 < 8; mt2++) {
            const int ra = (mt2 * 16 + l15) * 64;
            const bf16x8 ak0 = *(const bf16x8*)&Ks[ra + ((quad ^ l7) << 3)];
            const bf16x8 ak1 = *(const bf16x8*)&Ks[ra + (((4 | quad) ^ l7) << 3)];
            f32x4 s = (f32x4){0.f, 0.f, 0.f, 0.f};
            s = __builtin_amdgcn_mfma_f32_16x16x32_bf16(ak0, bq0, s, 0, 0, 0);
            s = __builtin_amdgcn_mfma_f32_16x16x32_bf16(ak1, bq1, s, 0, 0, 0);
            sa[mt2] = s;
        }
        __builtin_amdgcn_s_setprio(0);

        // scale (exp2 domain) + key-mask bias
        #pragma unroll
        for (int mt2 = 0; mt2 < 8; mt2++) {
            const float4 mv = *(const float4*)(mbb + jbase + mt2 * 16 + quad * 4);
            sa[mt2][0] = sa[mt2][0] * SCL2 + mv.x;
            sa[mt2][1] = sa[mt2][1] * SCL2 + mv.y;
            sa[mt2][2] = sa[mt2][2] * SCL2 + mv.z;
            sa[mt2][3] = sa[mt2][3] * SCL2 + mv.w;
        }
        // causal (+pad) mask: only the last tile contains the boundary
        if (jt == ntp - 1) {
            const int tl = qg + 4096 - jbase;
            #pragma unroll
            for (int mt2 = 0; mt2 < 8; mt2++)
                #pragma unroll
                for (int r = 0; r < 4; r++)
                    if (mt2 * 16 + quad * 4 + r > tl) sa[mt2][r] = -1.0e30f;
        }

        // softmax numerator: pure per-lane (no max, no cross-lane this tile)
        #pragma unroll
        for (int mt2 = 0; mt2 < 8; mt2++)
            #pragma unroll
            for (int r = 0; r < 4; r++) {
                const float pv = __builtin_amdgcn_exp2f(sa[mt2][r]);
                sa[mt2][r] = pv;
                l_i += pv;
            }

        // P -> Ps[q][key] (uint2 packed, truncation); same-wave rows, no barrier
        const int prow = (w * 16 + l15) * 128;
        #pragma unroll
        for (int mt2 = 0; mt2 < 8; mt2++) {
            const int u  = 2 * mt2 + (quad >> 1);
            const int up = (u & 8) | ((u ^ l7) & 7);
            uint2 pk;
            pk.x = pack2(sa[mt2][0], sa[mt2][1]);
            pk.y = pack2(sa[mt2][2], sa[mt2][3]);
            *(uint2*)&Ps[prow + up * 8 + (quad & 1) * 4] = pk;
        }

        // O^T += V^T.P^T
        __builtin_amdgcn_s_setprio(1);
        #pragma unroll
        for (int s = 0; s < 4; s++) {
            const int u  = quad + 4 * s;
            const int up = (u & 8) | ((u ^ l7) & 7);
            const bf16x8 bp = *(const bf16x8*)&Ps[prow + up * 8];
            #pragma unroll
            for (int mt = 0; mt < 4; mt++) {
                const bf16x8 av = *(const bf16x8*)&Vs[(mt * 16 + l15) * 128 + up * 8];
                oa[mt] = __builtin_amdgcn_mfma_f32_16x16x32_bf16(av, bp, oa[mt], 0, 0, 0);
            }
        }
        __builtin_amdgcn_s_setprio(0);
    }

    // epilogue: cross-quad l reduce (the 4 quads of the same l15 hold disjoint
    // key partials for q=qg), then normalize and store.
    float l = l_i;
    l += __shfl_xor(l, 16);
    l += __shfl_xor(l, 32);
    const float inv = 1.0f / l;
    unsigned short* arow = ao + ((size_t)(b * NQ + qg)) * 1024 + h * 64;
    #pragma unroll
    for (int mt = 0; mt < 4; mt++) {
        ush4 o;
        o[0] = f2bf(oa[mt][0] * inv); o[1] = f2bf(oa[mt][1] * inv);
        o[2] = f2bf(oa[mt][2] * inv); o[3] = f2bf(oa[mt][3] * inv);
        *(ush4*)(arow + mt * 16 + quad * 4) = o;
    }
}

// ---------------------------------------------------------------------------
extern "C" void kernel_launch(void* const* d_in, const int* in_sizes, int n_in,
                              void* d_out, int out_size, void* d_ws, size_t ws_size,
                              hipStream_t stream)
{
    const float* x        = (const float*)d_in[0];
    const float* mem      = (const float*)d_in[1];
    const unsigned char* mask = (const unsigned char*)d_in[2];
    const int*   rel_idxs = (const int*)d_in[3];
    const float* Wq       = (const float*)d_in[4];
    const float* Wk       = (const float*)d_in[5];
    const float* Wv       = (const float*)d_in[6];
    const float* Wo       = (const float*)d_in[7];
    const float* bo       = (const float*)d_in[8];
    const float* rel_table= (const float*)d_in[9];

    float* out = (float*)d_out;
    const size_t M1 = (size_t)1024 * 1024;
    unsigned short* xb   = (unsigned short*)d_ws;   //  2M
    unsigned short* memb = xb   + 2 * M1;           //  8M
    unsigned short* wt   = memb + 8 * M1;           //  4M
    unsigned short* qb   = wt   + 4 * M1;           //  2M  qh[b][h][q][dh]
    unsigned short* kb   = qb   + 2 * M1;           // 10M  kh[b][h][j][dh]
    unsigned short* vb   = kb   + 10 * M1;          // 10M  vt[b][h][dh][j]
    unsigned short* aob  = vb   + 10 * M1;          //  2M
    float* mbp = (float*)(aob + 2 * M1);            // 10240 floats

    prep_kernel<<<9256, 256, 0, stream>>>(
        x, mem, mask, Wq, Wk, Wv, Wo, xb, memb, wt, mbp);
    mgemm01_kernel<<<352, 512, 0, stream>>>(
        xb, memb, wt, qb, kb, vb, rel_table, rel_idxs);
    attn5_kernel<<<dim3(16, 16, 2), 256, 0, stream>>>(qb, kb, vb, mbp, aob);
    // last dispatch: out-projection (z=0) + new_mem copy (z=1)
    mgemm2_kernel<<<dim3(8, 32, 2), 256, 0, stream>>>(
        aob, wt + 3 * M1, out, bo, x, out + (size_t)2048 * 1024);
}

// Round 7
// 288.575 us; speedup vs baseline: 1.1642x; 1.0535x over previous
//
#include <hip/hip_runtime.h>
#include <float.h>

#define NQ    1024
#define JTOT  5120
#define MEML  4096
#define SCL2  0.18033688011112042f   /* 0.125 * log2(e) */

typedef __attribute__((ext_vector_type(8))) short bf16x8;
typedef __attribute__((ext_vector_type(8))) unsigned short ush8;
typedef __attribute__((ext_vector_type(4))) unsigned short ush4;
typedef __attribute__((ext_vector_type(4))) float f32x4;

static __device__ __forceinline__ unsigned short f2bf(float x) {
    union { float f; unsigned u; } v; v.f = x;
    unsigned r = (v.u + 0x7fffu + ((v.u >> 16) & 1u)) >> 16;   // RNE
    return (unsigned short)r;
}
// pack trunc-bf16(f0) (low) | trunc-bf16(f1) (high)
static __device__ __forceinline__ unsigned pack2(float f0, float f1) {
    union { float f; unsigned u; } a, b; a.f = f1; b.f = f0;
    return __builtin_amdgcn_perm(a.u, b.u, 0x07060302u);
}

static __device__ __forceinline__ void gld16(const void* g, void* l) {
    __builtin_amdgcn_global_load_lds(
        (const __attribute__((address_space(1))) unsigned int*)g,
        (__attribute__((address_space(3))) unsigned int*)l, 16, 0, 0);
}

// ---------------------------------------------------------------------------
// prep: one launch. blocks [0,1024): x->bf16; [1024,5120): mem->bf16;
// [5120,5160): mask->bias; [5160,9256): W transpose.
// ---------------------------------------------------------------------------
__global__ __launch_bounds__(256)
void prep_kernel(const float* __restrict__ x, const float* __restrict__ mem,
                 const unsigned char* __restrict__ mask,
                 const float* __restrict__ W0, const float* __restrict__ W1,
                 const float* __restrict__ W2, const float* __restrict__ W3,
                 unsigned short* __restrict__ xb, unsigned short* __restrict__ memb,
                 unsigned short* __restrict__ wt, float* __restrict__ mbp)
{
    __shared__ float Ts[32][33];
    const int bid = blockIdx.x;
    const int t   = threadIdx.x;
    if (bid < 5120) {
        const float* src = (bid < 1024) ? x : mem;
        unsigned short* dst = (bid < 1024) ? xb : memb;
        const size_t i = (size_t)((bid < 1024) ? bid : bid - 1024) * 2048 + t * 8;
        float4 a = *(const float4*)(src + i);
        float4 b = *(const float4*)(src + i + 4);
        ush8 o;
        o[0] = f2bf(a.x); o[1] = f2bf(a.y); o[2] = f2bf(a.z); o[3] = f2bf(a.w);
        o[4] = f2bf(b.x); o[5] = f2bf(b.y); o[6] = f2bf(b.z); o[7] = f2bf(b.w);
        *(ush8*)(dst + i) = o;
    } else if (bid < 5160) {
        const int i = (bid - 5120) * 256 + t;
        mbp[i] = mask[i] ? -1.0e30f : 0.0f;
    } else {
        const int idx = bid - 5160;
        const int z   = idx >> 10;
        const int rem = idx & 1023;
        const float* W = (z == 0) ? W0 : (z == 1) ? W1 : (z == 2) ? W2 : W3;
        unsigned short* D = wt + (size_t)z * 1024 * 1024;
        const int n0 = (rem & 31) * 32, k0 = (rem >> 5) * 32;
        const int tr = t >> 3, tc = (t & 7) * 4;
        float4 v = *(const float4*)(W + (size_t)(k0 + tr) * 1024 + n0 + tc);
        Ts[tr][tc + 0] = v.x; Ts[tr][tc + 1] = v.y;
        Ts[tr][tc + 2] = v.z; Ts[tr][tc + 3] = v.w;
        __syncthreads();
        ush4 o;
        o[0] = f2bf(Ts[tc + 0][tr]); o[1] = f2bf(Ts[tc + 1][tr]);
        o[2] = f2bf(Ts[tc + 2][tr]); o[3] = f2bf(Ts[tc + 3][tr]);
        *(ush4*)(D + (size_t)(n0 + tr) * 1024 + k0 + tc) = o;
    }
}

// ---------------------------------------------------------------------------
// Merged q/k/v GEMM — unchanged from R6 (verified: swizzle dropped it below
// attn; 256² tile, BK=64, 4-phase counted-vmcnt, chunked XCD swizzle).
// ---------------------------------------------------------------------------
__global__ __launch_bounds__(512, 2)
void mgemm01_kernel(const unsigned short* __restrict__ xb,
                    const unsigned short* __restrict__ memb,
                    const unsigned short* __restrict__ wt,
                    unsigned short* __restrict__ Qb, unsigned short* __restrict__ Kb,
                    unsigned short* __restrict__ Vb,
                    const float* __restrict__ rel_table, const int* __restrict__ rel_idxs)
{
    __shared__ unsigned short A1R0[128 * 64], A2R0[128 * 64];
    __shared__ unsigned short A1R1[128 * 64], A2R1[128 * 64];
    __shared__ unsigned short Bf0[256 * 64],  Bf1[256 * 64];

    const int t    = threadIdx.x;
    const int lane = t & 63;
    const int w    = t >> 6;          // 0..7
    const int wr   = w >> 2;          // 0..1  (M half)
    const int wc   = w & 3;           // 0..3  (N quarter)
    const int l15  = lane & 15;
    const int quad = lane >> 4;
    const int l7   = l15 & 7;
    const int srow = lane >> 3;                 // staging row within 8-row group
    const int scol = ((lane & 7) ^ srow) << 3;  // pre-swizzled source chunk

    const int bid = blockIdx.x;
    int mode, bx, by;
    if (bid < 96) {
        mode = 0;
        const int l = (bid & 7) * 12 + (bid >> 3);   // XCD-contiguous logical id
        bx = l >> 3;                                 // 0..11 (by-fastest: share bx)
        by = l & 7;                                  // 0..7
    } else {
        mode = 1;
        const int p   = bid - 96;                    // 96 % 8 == 0 -> p%8 == bid%8
        const int xcd = p & 7;
        const int i   = p >> 3;                      // 0..31 within XCD
        bx = i & 7;                                  // all 8 B panels per XCD
        by = (xcd << 2) + (i >> 3);                  // 4 contiguous A slices per XCD
    }
    const int mat = bx >> 2;
    const int n0  = (bx & 3) << 8;
    const int m0  = by << 8;
    const unsigned short* Ag = (mode == 0) ? xb : memb;
    const unsigned short* Bg = wt + (size_t)((mode == 0) ? mat : mat + 1) * 1024 * 1024;

    const size_t abase = (size_t)(m0 + srow) * 1024 + scol;
    const size_t bbase = (size_t)(n0 + srow) * 1024 + scol;

    auto stgB0 = [&](unsigned short* BO, int kt) {    // B rows [0,128)
        const int kb = kt << 6, r0 = w * 16;
        gld16(Bg + bbase + (size_t)r0 * 1024 + kb,       BO + r0 * 64);
        gld16(Bg + bbase + (size_t)(r0 + 8) * 1024 + kb, BO + (r0 + 8) * 64);
    };
    auto stgB1 = [&](unsigned short* BO, int kt) {    // B rows [128,256)
        const int kb = kt << 6, r0 = 128 + w * 16;
        gld16(Bg + bbase + (size_t)r0 * 1024 + kb,       BO + r0 * 64);
        gld16(Bg + bbase + (size_t)(r0 + 8) * 1024 + kb, BO + (r0 + 8) * 64);
    };
    auto stgA1 = [&](unsigned short* AO, int kt) {    // A rows [0,64) u [128,192)
        const int kb = kt << 6, r0 = w * 8;
        gld16(Ag + abase + (size_t)r0 * 1024 + kb,         AO + r0 * 64);
        gld16(Ag + abase + (size_t)(128 + r0) * 1024 + kb, AO + (64 + r0) * 64);
    };
    auto stgA2 = [&](unsigned short* AO, int kt) {    // A rows [64,128) u [192,256)
        const int kb = kt << 6, r0 = w * 8;
        gld16(Ag + abase + (size_t)(64 + r0) * 1024 + kb,  AO + r0 * 64);
        gld16(Ag + abase + (size_t)(192 + r0) * 1024 + kb, AO + (64 + r0) * 64);
    };

    f32x4 acc[8][4];
    #pragma unroll
    for (int i = 0; i < 8; i++)
        #pragma unroll
        for (int j = 0; j < 4; j++) acc[i][j] = (f32x4){0.f, 0.f, 0.f, 0.f};

    stgB0(Bf0, 0); stgB1(Bf0, 0); stgA1(A1R0, 0); stgA2(A2R0, 0);
    stgB0(Bf1, 1); stgA1(A1R1, 1); stgB1(Bf1, 1);
    asm volatile("s_waitcnt vmcnt(6)");
    __builtin_amdgcn_s_barrier();

    bf16x8 bfr[4][2];

#define PHASE(AO, MB, STAGE, VMW)                                                  \
    {                                                                              \
        const int Ra0 = (wr * 64 + ((MB) & 3) * 16 + l15) * 64;                    \
        const int Ra1 = Ra0 + 16 * 64;                                             \
        const bf16x8 a0 = *(const bf16x8*)&AO[Ra0 + ((quad ^ l7) << 3)];           \
        const bf16x8 a1 = *(const bf16x8*)&AO[Ra0 + (((4 | quad) ^ l7) << 3)];     \
        const bf16x8 a2 = *(const bf16x8*)&AO[Ra1 + ((quad ^ l7) << 3)];           \
        const bf16x8 a3 = *(const bf16x8*)&AO[Ra1 + (((4 | quad) ^ l7) << 3)];     \
        STAGE;                                                                     \
        __builtin_amdgcn_s_barrier();                                              \
        asm volatile("s_waitcnt lgkmcnt(0)");                                      \
        __builtin_amdgcn_sched_barrier(0);                                         \
        __builtin_amdgcn_s_setprio(1);                                             \
        _Pragma("unroll")                                                          \
        for (int n = 0; n < 4; n++) {                                              \
            acc[(MB)][n]     = __builtin_amdgcn_mfma_f32_16x16x32_bf16(a0, bfr[n][0], acc[(MB)][n], 0, 0, 0);     \
            acc[(MB)][n]     = __builtin_amdgcn_mfma_f32_16x16x32_bf16(a1, bfr[n][1], acc[(MB)][n], 0, 0, 0);     \
            acc[(MB) + 1][n] = __builtin_amdgcn_mfma_f32_16x16x32_bf16(a2, bfr[n][0], acc[(MB) + 1][n], 0, 0, 0); \
            acc[(MB) + 1][n] = __builtin_amdgcn_mfma_f32_16x16x32_bf16(a3, bfr[n][1], acc[(MB) + 1][n], 0, 0, 0); \
        }                                                                          \
        __builtin_amdgcn_s_setprio(0);                                             \
        VMW;                                                                       \
        __builtin_amdgcn_s_barrier();                                              \
    }

#define KSTEP(A1O, A2O, BO, S0, S1, S2, S3, VMW)                                   \
    {                                                                              \
        _Pragma("unroll")                                                          \
        for (int n = 0; n < 4; n++) {                                              \
            const int Rb = (wc * 64 + n * 16 + l15) * 64;                          \
            bfr[n][0] = *(const bf16x8*)&BO[Rb + ((quad ^ l7) << 3)];              \
            bfr[n][1] = *(const bf16x8*)&BO[Rb + (((4 | quad) ^ l7) << 3)];        \
        }                                                                          \
        PHASE(A1O, 0, S0, (void)0)                                                 \
        PHASE(A1O, 2, S1, (void)0)                                                 \
        PHASE(A2O, 4, S2, (void)0)                                                 \
        PHASE(A2O, 6, S3, VMW)                                                     \
    }

    for (int e = 0; e < 14; e += 2) {
        KSTEP(A1R0, A2R0, Bf0,
              stgA2(A2R1, e + 1),
              stgB0(Bf0, e + 2),
              stgA1(A1R0, e + 2),
              stgB1(Bf0, e + 2),
              asm volatile("s_waitcnt vmcnt(6)"))
        KSTEP(A1R1, A2R1, Bf1,
              stgA2(A2R0, e + 2),
              stgB0(Bf1, e + 3),
              stgA1(A1R1, e + 3),
              stgB1(Bf1, e + 3),
              asm volatile("s_waitcnt vmcnt(6)"))
    }
    KSTEP(A1R0, A2R0, Bf0, stgA2(A2R1, 15), (void)0, (void)0, (void)0,
          asm volatile("s_waitcnt vmcnt(0)"))
    KSTEP(A1R1, A2R1, Bf1, (void)0, (void)0, (void)0, (void)0, (void)0)

#undef KSTEP
#undef PHASE

    const bool isQ = (mode == 0) && (mat == 0);
    const bool isK = (mode == 0) ? (mat == 1) : (mat == 0);
    if (!isQ && !isK) {                              // V path
        #pragma unroll
        for (int m = 0; m < 8; m++) {
            const int r0 = m0 + wr * 128 + m * 16 + quad * 4;
            const int bb = (mode == 0) ? (r0 >> 10) : (r0 >> 12);
            const int j0 = (mode == 0) ? 4096 + (r0 & 1023) : (r0 & 4095);
            #pragma unroll
            for (int n = 0; n < 4; n++) {
                const int col = n0 + wc * 64 + n * 16 + l15;
                ush4 o;
                o[0] = f2bf(acc[m][n][0]); o[1] = f2bf(acc[m][n][1]);
                o[2] = f2bf(acc[m][n][2]); o[3] = f2bf(acc[m][n][3]);
                *(ush4*)(Vb + ((size_t)((bb * 16 + (col >> 6)) * 64 + (col & 63))) * JTOT + j0) = o;
            }
        }
    } else {
        #pragma unroll
        for (int m = 0; m < 8; m++)
            #pragma unroll
            for (int reg = 0; reg < 4; reg++) {
                const int r = m0 + wr * 128 + m * 16 + quad * 4 + reg;
                int bb, idx, chunk;
                if (mode == 0) { bb = r >> 10; idx = isK ? 4096 + (r & 1023) : (r & 1023); chunk = 4; }
                else           { bb = r >> 12; idx = r & 4095; chunk = idx >> 10; }
                #pragma unroll
                for (int n = 0; n < 4; n++) {
                    const int col = n0 + wc * 64 + n * 16 + l15;
                    const int hh = col >> 6, dh = col & 63;
                    float v = acc[m][n][reg];
                    if (isK) {
                        v += rel_table[rel_idxs[chunk] * 16 + hh];
                        Kb[((size_t)(bb * 16 + hh) * JTOT + idx) * 64 + dh] = f2bf(v);
                    } else {
                        Qb[((size_t)(bb * 16 + hh) * NQ + idx) * 64 + dh] = f2bf(v);
                    }
                }
            }
    }
}

// ---------------------------------------------------------------------------
// out = ao @ WoT + bo. 64x128 tile, BK=64, swizzled.
// z=1 blocks: copy x -> new_mem (LAST dispatch in graph — survives re-poison).
// ---------------------------------------------------------------------------
__global__ __launch_bounds__(256)
void mgemm2_kernel(const unsigned short* __restrict__ A,
                   const unsigned short* __restrict__ WT,
                   float* __restrict__ outF, const float* __restrict__ bo,
                   const float* __restrict__ x, float* __restrict__ newmem)
{
    __shared__ unsigned short Al[64 * 64];
    __shared__ unsigned short Bl[128 * 64];

    const int t = threadIdx.x;
    if (blockIdx.z == 1) {
        const int blk = blockIdx.y * 8 + blockIdx.x;      // 0..255
        const size_t base = (size_t)blk * 8192 + t * 4;
        #pragma unroll
        for (int i = 0; i < 8; i++)
            *(float4*)(newmem + base + (size_t)i * 1024) =
                *(const float4*)(x + base + (size_t)i * 1024);
        return;
    }

    const int lane = t & 63;
    const int w    = t >> 6;
    const int l15  = lane & 15;
    const int quad = lane >> 4;
    const int l7   = l15 & 7;
    const int n0   = blockIdx.x * 128;
    const int m0   = blockIdx.y * 64;

    f32x4 acc[4][2];
    #pragma unroll
    for (int i = 0; i < 4; i++)
        #pragma unroll
        for (int j = 0; j < 2; j++) acc[i][j] = (f32x4){0.f, 0.f, 0.f, 0.f};

    for (int k0 = 0; k0 < 1024; k0 += 64) {
        __syncthreads();
        #pragma unroll
        for (int it = 0; it < 2; it++) {
            const int lin  = it * 256 + t;
            const int row  = lin >> 3;
            const int colb = ((lin & 7) ^ (row & 7)) * 8;
            gld16(A + (size_t)(m0 + row) * 1024 + k0 + colb,
                  &Al[(size_t)(it * 256 + w * 64) * 8]);
        }
        #pragma unroll
        for (int it = 0; it < 4; it++) {
            const int lin  = it * 256 + t;
            const int row  = lin >> 3;
            const int colb = ((lin & 7) ^ (row & 7)) * 8;
            gld16(WT + (size_t)(n0 + row) * 1024 + k0 + colb,
                  &Bl[(size_t)(it * 256 + w * 64) * 8]);
        }
        __syncthreads();
        bf16x8 af[4][2], bfr[2][2];
        #pragma unroll
        for (int i = 0; i < 4; i++) {
            const int R = i * 16 + l15;
            af[i][0] = *(const bf16x8*)&Al[R * 64 + ((quad ^ l7) << 3)];
            af[i][1] = *(const bf16x8*)&Al[R * 64 + (((4 | quad) ^ l7) << 3)];
        }
        #pragma unroll
        for (int j = 0; j < 2; j++) {
            const int R = w * 32 + j * 16 + l15;
            bfr[j][0] = *(const bf16x8*)&Bl[R * 64 + ((quad ^ l7) << 3)];
            bfr[j][1] = *(const bf16x8*)&Bl[R * 64 + (((4 | quad) ^ l7) << 3)];
        }
        #pragma unroll
        for (int i = 0; i < 4; i++)
            #pragma unroll
            for (int j = 0; j < 2; j++) {
                acc[i][j] = __builtin_amdgcn_mfma_f32_16x16x32_bf16(af[i][0], bfr[j][0], acc[i][j], 0, 0, 0);
                acc[i][j] = __builtin_amdgcn_mfma_f32_16x16x32_bf16(af[i][1], bfr[j][1], acc[i][j], 0, 0, 0);
            }
    }

    #pragma unroll
    for (int i = 0; i < 4; i++)
        #pragma unroll
        for (int reg = 0; reg < 4; reg++) {
            const int r = m0 + i * 16 + quad * 4 + reg;
            #pragma unroll
            for (int j = 0; j < 2; j++) {
                const int col = n0 + w * 32 + j * 16 + l15;
                outF[(size_t)r * 1024 + col] = acc[i][j][reg] + bo[col];
            }
        }
}

// ---------------------------------------------------------------------------
// Flash attention, S^T formulation, 128-key tiles, swizzled LDS.
// R7 (attn6): two changes vs R6:
//  (1) XCD-group swizzle: flat block id remapped so each XCD owns 4 complete
//      (h,b) groups (16 qt-blocks each, all concurrent on its 32 CUs) -> K/V
//      working set ~5.2 MB/XCD ≈ L2-resident. Was: qt%8 spread the 16 blocks
//      sharing K/V over all 8 XCDs (FETCH 160 MB vs 45 MB unique).
//  (2) wave-owns-keys QK: all 4 waves hold ALL 64 Q-rows in regs (+32 VGPR);
//      wave w computes keys [32w,32w+32) x 64 q. K LDS reads drop 64->16 KB
//      per tile (was: every wave read the full Ks). Ps write u=4w+2kk+(q>>1)
//      (key = u*8+(quad&1)*4+r identity preserved; l7-swizzle row-consistent).
//      Costs: +1 barrier/tile (Ps now cross-wave), epilogue l-reduction via
//      Ls[4][64] (partials additive — no max tracking in this formulation).
// ---------------------------------------------------------------------------
__global__ __launch_bounds__(256)
void attn6_kernel(const unsigned short* __restrict__ qh,
                  const unsigned short* __restrict__ kh,
                  const unsigned short* __restrict__ vt,
                  const float* __restrict__ mb,
                  unsigned short* __restrict__ ao)
{
    __shared__ unsigned short Ks[128 * 64];   // [key][dh] swizzled (8-unit rows)
    __shared__ unsigned short Vs[64 * 128];   // [dh][key] swizzled (16-unit rows)
    __shared__ unsigned short Ps[64 * 128];   // [q][key]  swizzled (16-unit rows)
    __shared__ float Ls[4][64];               // per-source-wave l partials

    const int t    = threadIdx.x;
    const int lane = t & 63;
    const int w    = t >> 6;
    const int l15  = lane & 15;
    const int quad = lane >> 4;
    const int l7   = l15 & 7;

    // XCD-group swizzle: xcd = flat%8 (dispatch x-fastest); each XCD gets
    // 4 (h,b) groups x 16 qt blocks.
    const int flat = blockIdx.x + 16 * blockIdx.y + 256 * blockIdx.z;
    const int xcd  = flat & 7;
    const int idx  = flat >> 3;                  // 0..63
    const int qt   = idx >> 2;                   // 0..15
    const int hb   = (xcd << 2) | (idx & 3);     // 0..31
    const int h    = hb & 15;
    const int b    = hb >> 4;

    const int qbase = qt * 64;
    const int qg    = qbase + w * 16 + l15;

    // ALL 64 q-rows of the block in registers (qb = 0..3)
    bf16x8 bq0[4], bq1[4];
    #pragma unroll
    for (int qb = 0; qb < 4; qb++) {
        const unsigned short* qrow =
            qh + (((size_t)(b * 16 + h) * NQ + qbase + qb * 16 + l15) << 6);
        bq0[qb] = *(const bf16x8*)(qrow + quad * 8);
        bq1[qb] = *(const bf16x8*)(qrow + 32 + quad * 8);
    }

    const int krow = t >> 3;
    const int kcol = (t & 7) * 8;
    const int ksw  = ((t & 7) ^ (krow & 7)) * 8;
    const int vrow = t >> 4;
    const int vu   = t & 15;
    const int vcol = vu * 8;
    const int vsw  = ((vu & 8) | ((vu ^ (vrow & 7)) & 7)) * 8;

    const unsigned short* kbase = kh + (((size_t)(b * 16 + h) * JTOT) << 6);
    const unsigned short* vbase = vt + (((size_t)(b * 16 + h)) << 6) * JTOT;
    const float* mbb = mb + b * JTOT;

    f32x4 oa[4];
    #pragma unroll
    for (int mt = 0; mt < 4; mt++) oa[mt] = (f32x4){0.f, 0.f, 0.f, 0.f};
    float lacc[4] = {0.f, 0.f, 0.f, 0.f};     // per-lane, per-qb (this wave's keys)

    const int ntp = (qt + 66) >> 1;           // 128-key tiles (padded)

    ush8 kst[4], vst[4];
    #pragma unroll
    for (int p = 0; p < 4; p++)
        kst[p] = *(const ush8*)(kbase + ((size_t)(krow + 32 * p) << 6) + kcol);
    #pragma unroll
    for (int p = 0; p < 4; p++)
        vst[p] = *(const ush8*)(vbase + (size_t)(vrow + 16 * p) * JTOT + vcol);

    const int prow = (w * 16 + l15) * 128;    // PV read row (this wave's q)

    for (int jt = 0; jt < ntp; jt++) {
        const int jbase = jt * 128;
        __syncthreads();
        #pragma unroll
        for (int p = 0; p < 4; p++)
            *(ush8*)&Ks[(krow + 32 * p) * 64 + ksw] = kst[p];
        #pragma unroll
        for (int p = 0; p < 4; p++)
            *(ush8*)&Vs[(vrow + 16 * p) * 128 + vsw] = vst[p];
        __syncthreads();

        if (jt + 1 < ntp) {
            const int jb2 = jbase + 128;
            #pragma unroll
            for (int p = 0; p < 4; p++)
                kst[p] = *(const ush8*)(kbase + ((size_t)(jb2 + krow + 32 * p) << 6) + kcol);
            #pragma unroll
            for (int p = 0; p < 4; p++)
                vst[p] = *(const ush8*)(vbase + (size_t)(vrow + 16 * p) * JTOT + jb2 + vcol);
        }

        // QK^T: wave w owns keys [32w, 32w+32) x all 64 q
        f32x4 sa[2][4];
        __builtin_amdgcn_s_setprio(1);
        #pragma unroll
        for (int kk = 0; kk < 2; kk++) {
            const int mt2 = 2 * w + kk;
            const int ra  = (mt2 * 16 + l15) * 64;
            const bf16x8 ak0 = *(const bf16x8*)&Ks[ra + ((quad ^ l7) << 3)];
            const bf16x8 ak1 = *(const bf16x8*)&Ks[ra + (((4 | quad) ^ l7) << 3)];
            #pragma unroll
            for (int qb = 0; qb < 4; qb++) {
                f32x4 s = (f32x4){0.f, 0.f, 0.f, 0.f};
                s = __builtin_amdgcn_mfma_f32_16x16x32_bf16(ak0, bq0[qb], s, 0, 0, 0);
                s = __builtin_amdgcn_mfma_f32_16x16x32_bf16(ak1, bq1[qb], s, 0, 0, 0);
                sa[kk][qb] = s;
            }
        }
        __builtin_amdgcn_s_setprio(0);

        // scale (exp2 domain) + key-mask bias (key depends on kk only)
        #pragma unroll
        for (int kk = 0; kk < 2; kk++) {
            const float4 mv = *(const float4*)(mbb + jbase + (2 * w + kk) * 16 + quad * 4);
            #pragma unroll
            for (int qb = 0; qb < 4; qb++) {
                sa[kk][qb][0] = sa[kk][qb][0] * SCL2 + mv.x;
                sa[kk][qb][1] = sa[kk][qb][1] * SCL2 + mv.y;
                sa[kk][qb][2] = sa[kk][qb][2] * SCL2 + mv.z;
                sa[kk][qb][3] = sa[kk][qb][3] * SCL2 + mv.w;
            }
        }
        // causal (+pad) mask: only the last tile contains the boundary
        if (jt == ntp - 1) {
            #pragma unroll
            for (int qb = 0; qb < 4; qb++) {
                const int tl = qbase + qb * 16 + l15 + 4096 - jbase;
                #pragma unroll
                for (int kk = 0; kk < 2; kk++)
                    #pragma unroll
                    for (int r = 0; r < 4; r++)
                        if ((2 * w + kk) * 16 + quad * 4 + r > tl) sa[kk][qb][r] = -1.0e30f;
            }
        }

        // softmax numerator (per-lane); l partial per (lane, qb)
        #pragma unroll
        for (int kk = 0; kk < 2; kk++)
            #pragma unroll
            for (int qb = 0; qb < 4; qb++)
                #pragma unroll
                for (int r = 0; r < 4; r++) {
                    const float pv = __builtin_amdgcn_exp2f(sa[kk][qb][r]);
                    sa[kk][qb][r] = pv;
                    lacc[qb] += pv;
                }

        // P -> Ps[q][key]: rows qb*16+l15, key-group u = 4w + 2kk + (quad>>1)
        #pragma unroll
        for (int kk = 0; kk < 2; kk++) {
            const int u  = 4 * w + 2 * kk + (quad >> 1);
            const int up = (u & 8) | ((u ^ l7) & 7);
            #pragma unroll
            for (int qb = 0; qb < 4; qb++) {
                uint2 pk;
                pk.x = pack2(sa[kk][qb][0], sa[kk][qb][1]);
                pk.y = pack2(sa[kk][qb][2], sa[kk][qb][3]);
                *(uint2*)&Ps[(qb * 16 + l15) * 128 + up * 8 + (quad & 1) * 4] = pk;
            }
        }
        __syncthreads();          // Ps is cross-wave now

        // O^T += V^T.P^T (each wave: its 16 q, full key range)
        __builtin_amdgcn_s_setprio(1);
        #pragma unroll
        for (int s = 0; s < 4; s++) {
            const int u  = quad + 4 * s;
            const int up = (u & 8) | ((u ^ l7) & 7);
            const bf16x8 bp = *(const bf16x8*)&Ps[prow + up * 8];
            #pragma unroll
            for (int mt = 0; mt < 4; mt++) {
                const bf16x8 av = *(const bf16x8*)&Vs[(mt * 16 + l15) * 128 + up * 8];
                oa[mt] = __builtin_amdgcn_mfma_f32_16x16x32_bf16(av, bp, oa[mt], 0, 0, 0);
            }
        }
        __builtin_amdgcn_s_setprio(0);
    }

    // epilogue: l = sum over quads (shfl) and waves (Ls) of lacc partials.
    #pragma unroll
    for (int qb = 0; qb < 4; qb++) {
        lacc[qb] += __shfl_xor(lacc[qb], 16);
        lacc[qb] += __shfl_xor(lacc[qb], 32);
    }
    if (quad == 0) {
        #pragma unroll
        for (int qb = 0; qb < 4; qb++) Ls[w][qb * 16 + l15] = lacc[qb];
    }
    __syncthreads();
    const float l = Ls[0][w * 16 + l15] + Ls[1][w * 16 + l15] +
                    Ls[2][w * 16 + l15] + Ls[3][w * 16 + l15];
    const float inv = 1.0f / l;
    unsigned short* arow = ao + ((size_t)(b * NQ + qg)) * 1024 + h * 64;
    #pragma unroll
    for (int mt = 0; mt < 4; mt++) {
        ush4 o;
        o[0] = f2bf(oa[mt][0] * inv); o[1] = f2bf(oa[mt][1] * inv);
        o[2] = f2bf(oa[mt][2] * inv); o[3] = f2bf(oa[mt][3] * inv);
        *(ush4*)(arow + mt * 16 + quad * 4) = o;
    }
}

// ---------------------------------------------------------------------------
extern "C" void kernel_launch(void* const* d_in, const int* in_sizes, int n_in,
                              void* d_out, int out_size, void* d_ws, size_t ws_size,
                              hipStream_t stream)
{
    const float* x        = (const float*)d_in[0];
    const float* mem      = (const float*)d_in[1];
    const unsigned char* mask = (const unsigned char*)d_in[2];
    const int*   rel_idxs = (const int*)d_in[3];
    const float* Wq       = (const float*)d_in[4];
    const float* Wk       = (const float*)d_in[5];
    const float* Wv       = (const float*)d_in[6];
    const float* Wo       = (const float*)d_in[7];
    const float* bo       = (const float*)d_in[8];
    const float* rel_table= (const float*)d_in[9];

    float* out = (float*)d_out;
    const size_t M1 = (size_t)1024 * 1024;
    unsigned short* xb   = (unsigned short*)d_ws;   //  2M
    unsigned short* memb = xb   + 2 * M1;           //  8M
    unsigned short* wt   = memb + 8 * M1;           //  4M
    unsigned short* qb   = wt   + 4 * M1;           //  2M  qh[b][h][q][dh]
    unsigned short* kb   = qb   + 2 * M1;           // 10M  kh[b][h][j][dh]
    unsigned short* vb   = kb   + 10 * M1;          // 10M  vt[b][h][dh][j]
    unsigned short* aob  = vb   + 10 * M1;          //  2M
    float* mbp = (float*)(aob + 2 * M1);            // 10240 floats

    prep_kernel<<<9256, 256, 0, stream>>>(
        x, mem, mask, Wq, Wk, Wv, Wo, xb, memb, wt, mbp);
    mgemm01_kernel<<<352, 512, 0, stream>>>(
        xb, memb, wt, qb, kb, vb, rel_table, rel_idxs);
    attn6_kernel<<<dim3(16, 16, 2), 256, 0, stream>>>(qb, kb, vb, mbp, aob);
    // last dispatch: out-projection (z=0) + new_mem copy (z=1)
    mgemm2_kernel<<<dim3(8, 32, 2), 256, 0, stream>>>(
        aob, wt + 3 * M1, out, bo, x, out + (size_t)2048 * 1024);
}